// Round 2
// baseline (352.994 us; speedup 1.0000x reference)
//
#include <hip/hip_runtime.h>

#define HDIM 128
#define XDIM 66
#define EDIM 6
#define NGRAPHS 256
#define LN_EPS 1e-5f

// ---------------- K1: degree histograms of edge_index ----------------
__global__ void k_hist(const int* __restrict__ ei, float* __restrict__ c_src,
                       float* __restrict__ c_dst, int E) {
    int e = blockIdx.x * blockDim.x + threadIdx.x;
    if (e < E) {
        atomicAdd(&c_src[ei[e]], 1.0f);
        atomicAdd(&c_dst[ei[E + e]], 1.0f);
    }
}

// ---------------- K2: column-sum of edge_attr (E,6) ----------------
__global__ __launch_bounds__(256) void k_edgesum(const float* __restrict__ ea,
                                                 float* __restrict__ sum_attr, int E) {
    int nchunk = E >> 1;  // 12 floats (2 edges) per chunk
    float a0 = 0, a1 = 0, a2 = 0, a3 = 0, a4 = 0, a5 = 0;
    for (int c = blockIdx.x * blockDim.x + threadIdx.x; c < nchunk;
         c += gridDim.x * blockDim.x) {
        const float4* p = (const float4*)(ea + (size_t)c * 12);
        float4 v0 = p[0], v1 = p[1], v2 = p[2];
        a0 += v0.x + v1.z;  a1 += v0.y + v1.w;  a2 += v0.z + v2.x;
        a3 += v0.w + v2.y;  a4 += v1.x + v2.z;  a5 += v1.y + v2.w;
    }
#pragma unroll
    for (int m = 32; m; m >>= 1) {
        a0 += __shfl_xor(a0, m); a1 += __shfl_xor(a1, m); a2 += __shfl_xor(a2, m);
        a3 += __shfl_xor(a3, m); a4 += __shfl_xor(a4, m); a5 += __shfl_xor(a5, m);
    }
    __shared__ float sbuf[4][6];
    int lane = threadIdx.x & 63, w = threadIdx.x >> 6;
    if (lane == 0) {
        sbuf[w][0] = a0; sbuf[w][1] = a1; sbuf[w][2] = a2;
        sbuf[w][3] = a3; sbuf[w][4] = a4; sbuf[w][5] = a5;
    }
    __syncthreads();
    if (threadIdx.x < 6) {
        float s = sbuf[0][threadIdx.x] + sbuf[1][threadIdx.x] +
                  sbuf[2][threadIdx.x] + sbuf[3][threadIdx.x];
        atomicAdd(&sum_attr[threadIdx.x], s);
    }
    if (blockIdx.x == 0 && threadIdx.x < 6 && (E & 1))
        atomicAdd(&sum_attr[threadIdx.x], ea[(size_t)(E - 1) * 6 + threadIdx.x]);
}

// ---------------- K3: weighted column sums of x: xs[0..65]=Σ c_src[n]x[n][k], xs[66..131]=Σ c_dst ----------------
__global__ __launch_bounds__(256) void k_xsum(const float* __restrict__ x,
        const float* __restrict__ c_src, const float* __restrict__ c_dst,
        float* __restrict__ xs, int N) {
    int lane = threadIdx.x & 63, w = threadIdx.x >> 6;
    int wid = blockIdx.x * 4 + w;
    int nw = gridDim.x * 4;
    float as0 = 0, ad0 = 0, as1 = 0, ad1 = 0;
    for (int n = wid; n < N; n += nw) {
        int nu = __builtin_amdgcn_readfirstlane(n);
        const float* xr = x + (size_t)nu * XDIM;
        float cs = c_src[nu], cd = c_dst[nu];
        float v0 = xr[lane];
        as0 = fmaf(cs, v0, as0);
        ad0 = fmaf(cd, v0, ad0);
        if (lane < 2) {
            float v1 = xr[64 + lane];
            as1 = fmaf(cs, v1, as1);
            ad1 = fmaf(cd, v1, ad1);
        }
    }
    __shared__ float redS[4][XDIM], redD[4][XDIM];
    redS[w][lane] = as0;  redD[w][lane] = ad0;
    if (lane < 2) { redS[w][64 + lane] = as1;  redD[w][64 + lane] = ad1; }
    __syncthreads();
    int t = threadIdx.x;
    if (t < XDIM) {
        atomicAdd(&xs[t],        redS[0][t] + redS[1][t] + redS[2][t] + redS[3][t]);
        atomicAdd(&xs[XDIM + t], redD[0][t] + redD[1][t] + redD[2][t] + redD[3][t]);
    }
}

// ---------------- K4: layer-0 s_src/s_dst from xs (s = xs @ w_node + E*b_node) ----------------
__global__ __launch_bounds__(256) void k_s0(const float* __restrict__ xs,
        const float* __restrict__ w_node, const float* __restrict__ b_node,
        float* __restrict__ sbuf0, float Ef) {
    int t = threadIdx.x;
    int col = t & 127, which = t >> 7;  // 0: src, 1: dst
    const float* v = xs + which * XDIM;
    float acc = Ef * b_node[col];
#pragma unroll
    for (int k = 0; k < XDIM; ++k) acc = fmaf(v[k], w_node[k * HDIM + col], acc);
    sbuf0[which * 256 + col] = acc;  // [0..127]=s_src, [256..383]=s_dst (rest zero)
}

// ---------------- K5: reduce per-block partials -> sbuf[512] ----------------
__global__ __launch_bounds__(256) void k_red(const float* __restrict__ partials,
                                             float* __restrict__ sbuf, int nb) {
    int b0 = blockIdx.x * 32;
    int b1 = min(nb, b0 + 32);
    int t = threadIdx.x;
    float s0 = 0.f, s1 = 0.f;
    for (int b = b0; b < b1; ++b) {
        const float* row = partials + (size_t)b * 512;
        s0 += row[t];
        s1 += row[t + 256];
    }
    atomicAdd(&sbuf[t], s0);
    atomicAdd(&sbuf[t + 256], s1);
}

// ---------------- K6: mean_msg = ([s_src,s_dst,se] @ W)/E + mp_b  (8 blocks x 16 cols) ----------------
__global__ __launch_bounds__(256) void k_mm(const float* __restrict__ sbuf,
        const float* __restrict__ sum_attr, const float* __restrict__ w_edge,
        const float* __restrict__ b_edge, const float* __restrict__ W,
        const float* __restrict__ mpb, float* __restrict__ mean_msg, float Ef) {
    __shared__ float sc[384];
    __shared__ float mred[256];
    int t = threadIdx.x;
    if (t < 128) {
        sc[t]       = sbuf[t]       + sbuf[t + 128];
        sc[128 + t] = sbuf[256 + t] + sbuf[384 + t];
        float se = Ef * b_edge[t];
#pragma unroll
        for (int k = 0; k < EDIM; ++k) se = fmaf(sum_attr[k], w_edge[k * HDIM + t], se);
        sc[256 + t] = se;
    }
    __syncthreads();
    int col = blockIdx.x * 16 + (t & 15);
    int rg = t >> 4;  // 16 groups x 24 rows
    float acc = 0.f;
#pragma unroll 4
    for (int r = rg * 24; r < rg * 24 + 24; ++r)
        acc = fmaf(sc[r], W[r * HDIM + col], acc);
    mred[t] = acc;
    __syncthreads();
    if (t < 16) {
        float s = 0.f;
#pragma unroll
        for (int g = 0; g < 16; ++g) s += mred[g * 16 + t];
        mean_msg[blockIdx.x * 16 + t] = s / Ef + mpb[blockIdx.x * 16 + t];
    }
}

// ---------------- K7: fused layer-0: h = relu(LN(x@w_node + b + mm)), + weighted sums ----------------
__global__ __launch_bounds__(256) void k_upd0(const float* __restrict__ x,
        const float* __restrict__ w_node, const float* __restrict__ b_node,
        const float* __restrict__ mean_msg, const float* __restrict__ ln_g,
        const float* __restrict__ ln_b, const float* __restrict__ c_src,
        const float* __restrict__ c_dst, float* __restrict__ h,
        float* __restrict__ partials, int N, int cpb) {
    __shared__ float ws[XDIM * HDIM];
    __shared__ float sb[HDIM], db[HDIM];
    int t = threadIdx.x;
    for (int i = t; i < XDIM * HDIM; i += 256) ws[i] = w_node[i];
    if (t < HDIM) { sb[t] = 0.f; db[t] = 0.f; }
    int lane = t & 63, w = t >> 6;
    int c0 = lane * 2;
    float2 bn = *(const float2*)(b_node + c0);
    float2 mm = *(const float2*)(mean_msg + c0);
    float2 g  = *(const float2*)(ln_g + c0);
    float2 bb = *(const float2*)(ln_b + c0);
    float2 base = {bn.x + mm.x, bn.y + mm.y};
    __syncthreads();
    int start = blockIdx.x * cpb;
    int end = min(N, start + cpb);
    int spw = (cpb + 3) >> 2;
    int ns = start + w * spw;
    int ne = min(end, ns + spw);
    float2 accS = {0.f, 0.f}, accD = {0.f, 0.f};
    for (int n0 = ns; n0 < ne; n0 += 2) {
        int nu0 = __builtin_amdgcn_readfirstlane(n0);
        bool two = (n0 + 1 < ne);
        int nu1 = two ? nu0 + 1 : nu0;
        const float* xr0 = x + (size_t)nu0 * XDIM;
        const float* xr1 = x + (size_t)nu1 * XDIM;
        float2 a0 = base, a1 = base;
#pragma unroll
        for (int k = 0; k < XDIM; ++k) {
            float2 wv = *(const float2*)&ws[k * HDIM + c0];
            float xk0 = xr0[k], xk1 = xr1[k];
            a0.x = fmaf(xk0, wv.x, a0.x);  a0.y = fmaf(xk0, wv.y, a0.y);
            a1.x = fmaf(xk1, wv.x, a1.x);  a1.y = fmaf(xk1, wv.y, a1.y);
        }
#pragma unroll 2
        for (int rr = 0; rr < 2; ++rr) {
            if (rr == 1 && !two) break;
            float2 a = rr ? a1 : a0;
            int nu = rr ? nu1 : nu0;
            float s = a.x + a.y;
#pragma unroll
            for (int m = 32; m; m >>= 1) s += __shfl_xor(s, m);
            float mu = s * (1.0f / HDIM);
            float dx = a.x - mu, dy = a.y - mu;
            float q = dx * dx + dy * dy;
#pragma unroll
            for (int m = 32; m; m >>= 1) q += __shfl_xor(q, m);
            float rs = rsqrtf(q * (1.0f / HDIM) + LN_EPS);
            float2 o;
            o.x = fmaxf(0.f, fmaf(dx * rs, g.x, bb.x));
            o.y = fmaxf(0.f, fmaf(dy * rs, g.y, bb.y));
            *(float2*)(h + (size_t)nu * HDIM + c0) = o;
            float cs = c_src[nu], cd = c_dst[nu];
            accS.x = fmaf(cs, o.x, accS.x);  accS.y = fmaf(cs, o.y, accS.y);
            accD.x = fmaf(cd, o.x, accD.x);  accD.y = fmaf(cd, o.y, accD.y);
        }
    }
    __syncthreads();
    atomicAdd(&sb[c0], accS.x);  atomicAdd(&sb[c0 + 1], accS.y);
    atomicAdd(&db[c0], accD.x);  atomicAdd(&db[c0 + 1], accD.y);
    __syncthreads();
    float* row = partials + (size_t)blockIdx.x * 512;
    if (t < 128) {
        row[t] = sb[t];        row[t + 128] = 0.f;
        row[t + 256] = db[t];  row[t + 384] = 0.f;
    }
}

// ---------------- K8: h = relu(LN(h + mm)); next-layer sums or pooling ----------------
template <int LAST>
__global__ __launch_bounds__(256) void k_update(
        float* __restrict__ h, const float* __restrict__ mean_msg,
        const float* __restrict__ ln_g, const float* __restrict__ ln_b,
        const float* __restrict__ c_src, const float* __restrict__ c_dst,
        const int* __restrict__ batch, float* __restrict__ partials,
        float* __restrict__ pooled, int N, int cpb) {
    int t = threadIdx.x;
    int lane = t & 63, w = t >> 6;
    int c0 = lane * 2;
    float2 mm = *(const float2*)(mean_msg + c0);
    float2 g  = *(const float2*)(ln_g + c0);
    float2 bb = *(const float2*)(ln_b + c0);
    int start = blockIdx.x * cpb;
    int end = min(N, start + cpb);
    int spw = (cpb + 3) >> 2;
    int nws = start + w * spw;
    int nwe = min(end, nws + spw);
    float2 accS = {0.f, 0.f}, accD = {0.f, 0.f}, accP = {0.f, 0.f};
    int cur_g = -1;
    for (int n = nws; n < nwe; ++n) {
        float2 v = *(const float2*)(h + (size_t)n * HDIM + c0);
        v.x += mm.x; v.y += mm.y;
        float s = v.x + v.y;
#pragma unroll
        for (int m = 32; m; m >>= 1) s += __shfl_xor(s, m);
        float mu = s * (1.0f / HDIM);
        float dx = v.x - mu, dy = v.y - mu;
        float q = dx * dx + dy * dy;
#pragma unroll
        for (int m = 32; m; m >>= 1) q += __shfl_xor(q, m);
        float rs = rsqrtf(q * (1.0f / HDIM) + LN_EPS);
        float2 o;
        o.x = fmaxf(0.f, fmaf(dx * rs, g.x, bb.x));
        o.y = fmaxf(0.f, fmaf(dy * rs, g.y, bb.y));
        if (LAST) {
            int gg = batch[n];
            if (gg != cur_g) {
                if (cur_g >= 0) {
                    atomicAdd(&pooled[cur_g * HDIM + c0],     accP.x);
                    atomicAdd(&pooled[cur_g * HDIM + c0 + 1], accP.y);
                }
                accP.x = 0.f; accP.y = 0.f;
                cur_g = gg;
            }
            accP.x += o.x; accP.y += o.y;
        } else {
            *(float2*)(h + (size_t)n * HDIM + c0) = o;
            float cs = c_src[n], cd = c_dst[n];
            accS.x = fmaf(cs, o.x, accS.x); accS.y = fmaf(cs, o.y, accS.y);
            accD.x = fmaf(cd, o.x, accD.x); accD.y = fmaf(cd, o.y, accD.y);
        }
    }
    if (LAST) {
        if (cur_g >= 0) {
            atomicAdd(&pooled[cur_g * HDIM + c0],     accP.x);
            atomicAdd(&pooled[cur_g * HDIM + c0 + 1], accP.y);
        }
    } else {
        __shared__ float sb[HDIM], db[HDIM];
        if (t < HDIM) { sb[t] = 0.f; db[t] = 0.f; }
        __syncthreads();
        atomicAdd(&sb[c0], accS.x); atomicAdd(&sb[c0 + 1], accS.y);
        atomicAdd(&db[c0], accD.x); atomicAdd(&db[c0 + 1], accD.y);
        __syncthreads();
        float* row = partials + (size_t)blockIdx.x * 512;
        if (t < 128) {
            row[t] = sb[t];        row[t + 128] = 0.f;
            row[t + 256] = db[t];  row[t + 384] = 0.f;
        }
    }
}

// ---------------- K9: out = (pooled / max(cnt,1)) @ w_out + b_out ----------------
__global__ __launch_bounds__(128) void k_out(const float* __restrict__ pooled,
        const int* __restrict__ batch, const float* __restrict__ w_out,
        const float* __restrict__ b_out, float* __restrict__ out, int N) {
    int gph = blockIdx.x;
    int t = threadIdx.x;
    __shared__ float p[HDIM];
    __shared__ int cntS;
    if (t == 0) {
        int lo = 0, hi = N;
        while (lo < hi) { int mid = (lo + hi) >> 1; if (batch[mid] < gph) lo = mid + 1; else hi = mid; }
        int lo2 = lo, hi2 = N;
        while (lo2 < hi2) { int mid = (lo2 + hi2) >> 1; if (batch[mid] <= gph) lo2 = mid + 1; else hi2 = mid; }
        cntS = lo2 - lo;
    }
    __syncthreads();
    float inv = 1.0f / fmaxf((float)cntS, 1.0f);
    p[t] = pooled[gph * HDIM + t] * inv;
    __syncthreads();
    float acc = b_out[t];
#pragma unroll 8
    for (int k = 0; k < HDIM; ++k) acc = fmaf(p[k], w_out[k * HDIM + t], acc);
    out[gph * HDIM + t] = acc;
}

extern "C" void kernel_launch(void* const* d_in, const int* in_sizes, int n_in,
                              void* d_out, int out_size, void* d_ws, size_t ws_size,
                              hipStream_t stream) {
    const float* x      = (const float*)d_in[0];
    const int*   ei     = (const int*)d_in[1];
    const float* ea     = (const float*)d_in[2];
    const int*   batch  = (const int*)d_in[3];
    const float* w_node = (const float*)d_in[4];
    const float* b_node = (const float*)d_in[5];
    const float* w_edge = (const float*)d_in[6];
    const float* b_edge = (const float*)d_in[7];
    const float* mp_w   = (const float*)d_in[8];
    const float* mp_b   = (const float*)d_in[9];
    const float* ln_g   = (const float*)d_in[10];
    const float* ln_b   = (const float*)d_in[11];
    const float* w_out  = (const float*)d_in[12];
    const float* b_out  = (const float*)d_in[13];
    float* out = (float*)d_out;
    int N = in_sizes[3];
    int E = in_sizes[2] / EDIM;
    float Ef = (float)E;

    float* ws = (float*)d_ws;
    size_t off = 0;
    float* h        = ws + off; off += (size_t)N * HDIM;
    float* partials = ws + off; off += (size_t)1024 * 512;
    float* mean_msg = ws + off; off += 128;
    // ---- accumulator region (contiguous, re-zeroed every call) ----
    float* acc0     = ws + off;
    float* c_src    = ws + off; off += N;
    float* c_dst    = ws + off; off += N;
    float* sum_attr = ws + off; off += 8;
    float* xs       = ws + off; off += 136;
    float* sbuf0    = ws + off; off += 512;
    float* sbuf1    = ws + off; off += 512;
    float* sbuf2    = ws + off; off += 512;
    float* pooled   = ws + off; off += NGRAPHS * HDIM;
    size_t zero_count = (size_t)(ws + off - acc0);
    hipMemsetAsync(acc0, 0, zero_count * sizeof(float), stream);

    k_hist<<<(E + 255) / 256, 256, 0, stream>>>(ei, c_src, c_dst, E);
    k_edgesum<<<128, 256, 0, stream>>>(ea, sum_attr, E);
    k_xsum<<<1024, 256, 0, stream>>>(x, c_src, c_dst, xs, N);
    k_s0<<<1, 256, 0, stream>>>(xs, w_node, b_node, sbuf0, Ef);

    const int NB = 1024;
    int cpb = (N + NB - 1) / NB;

    // layer 0
    k_mm<<<8, 256, 0, stream>>>(sbuf0, sum_attr, w_edge, b_edge,
                                mp_w, mp_b, mean_msg, Ef);
    k_upd0<<<NB, 256, 0, stream>>>(x, w_node, b_node, mean_msg, ln_g, ln_b,
                                   c_src, c_dst, h, partials, N, cpb);
    // layer 1
    k_red<<<NB / 32, 256, 0, stream>>>(partials, sbuf1, NB);
    k_mm<<<8, 256, 0, stream>>>(sbuf1, sum_attr, w_edge, b_edge,
                                mp_w + (size_t)1 * 384 * HDIM,
                                mp_b + (size_t)1 * HDIM, mean_msg, Ef);
    k_update<0><<<NB, 256, 0, stream>>>(h, mean_msg, ln_g, ln_b, c_src, c_dst,
                                        batch, partials, pooled, N, cpb);
    // layer 2
    k_red<<<NB / 32, 256, 0, stream>>>(partials, sbuf2, NB);
    k_mm<<<8, 256, 0, stream>>>(sbuf2, sum_attr, w_edge, b_edge,
                                mp_w + (size_t)2 * 384 * HDIM,
                                mp_b + (size_t)2 * HDIM, mean_msg, Ef);
    k_update<1><<<NB, 256, 0, stream>>>(h, mean_msg, ln_g, ln_b, c_src, c_dst,
                                        batch, partials, pooled, N, cpb);

    k_out<<<NGRAPHS, HDIM, 0, stream>>>(pooled, batch, w_out, b_out, out, N);
}

// Round 3
// 276.513 us; speedup vs baseline: 1.2766x; 1.2766x over previous
//
#include <hip/hip_runtime.h>

#define HDIM 128
#define XDIM 66
#define EDIM 6
#define NGRAPHS 256
#define LN_EPS 1e-5f
#define T0ROWS 64

// ---------------- K1: degree histograms of edge_index ----------------
__global__ void k_hist(const int* __restrict__ ei, float* __restrict__ c_src,
                       float* __restrict__ c_dst, int E) {
    int e = blockIdx.x * blockDim.x + threadIdx.x;
    if (e < E) {
        atomicAdd(&c_src[ei[e]], 1.0f);
        atomicAdd(&c_dst[ei[E + e]], 1.0f);
    }
}

// ---------------- K2: column-sum of edge_attr (E,6) ----------------
__global__ __launch_bounds__(256) void k_edgesum(const float* __restrict__ ea,
                                                 float* __restrict__ sum_attr, int E) {
    int nchunk = E >> 1;
    float a0 = 0, a1 = 0, a2 = 0, a3 = 0, a4 = 0, a5 = 0;
    for (int c = blockIdx.x * blockDim.x + threadIdx.x; c < nchunk;
         c += gridDim.x * blockDim.x) {
        const float4* p = (const float4*)(ea + (size_t)c * 12);
        float4 v0 = p[0], v1 = p[1], v2 = p[2];
        a0 += v0.x + v1.z;  a1 += v0.y + v1.w;  a2 += v0.z + v2.x;
        a3 += v0.w + v2.y;  a4 += v1.x + v2.z;  a5 += v1.y + v2.w;
    }
#pragma unroll
    for (int m = 32; m; m >>= 1) {
        a0 += __shfl_xor(a0, m); a1 += __shfl_xor(a1, m); a2 += __shfl_xor(a2, m);
        a3 += __shfl_xor(a3, m); a4 += __shfl_xor(a4, m); a5 += __shfl_xor(a5, m);
    }
    __shared__ float sbuf[4][6];
    int lane = threadIdx.x & 63, w = threadIdx.x >> 6;
    if (lane == 0) {
        sbuf[w][0] = a0; sbuf[w][1] = a1; sbuf[w][2] = a2;
        sbuf[w][3] = a3; sbuf[w][4] = a4; sbuf[w][5] = a5;
    }
    __syncthreads();
    if (threadIdx.x < 6) {
        float s = sbuf[0][threadIdx.x] + sbuf[1][threadIdx.x] +
                  sbuf[2][threadIdx.x] + sbuf[3][threadIdx.x];
        atomicAdd(&sum_attr[threadIdx.x], s);
    }
    if (blockIdx.x == 0 && threadIdx.x < 6 && (E & 1))
        atomicAdd(&sum_attr[threadIdx.x], ea[(size_t)(E - 1) * 6 + threadIdx.x]);
}

// ---------------- K3: weighted column sums of x (coalesced, no scalar loads) ----------------
__global__ __launch_bounds__(256) void k_xsum(const float* __restrict__ x,
        const float* __restrict__ c_src, const float* __restrict__ c_dst,
        float* __restrict__ xs, int N, int ntiles) {
    int lane = threadIdx.x & 63, w = threadIdx.x >> 6;
    int wid = blockIdx.x * 4 + w, nw = gridDim.x * 4;
    float as0 = 0, ad0 = 0, as1 = 0, ad1 = 0;
    for (int tt = wid; tt < ntiles; tt += nw) {
        int base = tt * 64;
        int nrows = min(64, N - base);
        float cvS = c_src[base + lane];   // c arrays padded past N -> safe
        float cvD = c_dst[base + lane];
        for (int r = 0; r < nrows; ++r) {
            const float* xr = x + (size_t)(base + r) * XDIM;
            float cs = __shfl(cvS, r);
            float cd = __shfl(cvD, r);
            float xv = xr[lane];          // coalesced 256B
            as0 = fmaf(cs, xv, as0);
            ad0 = fmaf(cd, xv, ad0);
            if (lane < 2) {
                float xe = xr[64 + lane];
                as1 = fmaf(cs, xe, as1);
                ad1 = fmaf(cd, xe, ad1);
            }
        }
    }
    atomicAdd(&xs[lane], as0);
    atomicAdd(&xs[XDIM + lane], ad0);
    if (lane < 2) {
        atomicAdd(&xs[64 + lane], as1);
        atomicAdd(&xs[XDIM + 64 + lane], ad1);
    }
}

// ---------------- K4: layer-0 s_src/s_dst from xs ----------------
__global__ __launch_bounds__(256) void k_s0(const float* __restrict__ xs,
        const float* __restrict__ w_node, const float* __restrict__ b_node,
        float* __restrict__ sbuf0, float Ef) {
    int t = threadIdx.x;
    int col = t & 127, which = t >> 7;
    const float* v = xs + which * XDIM;
    float acc = Ef * b_node[col];
#pragma unroll
    for (int k = 0; k < XDIM; ++k) acc = fmaf(v[k], w_node[k * HDIM + col], acc);
    sbuf0[which * 256 + col] = acc;
}

// ---------------- K5: reduce per-block partials -> sbuf[512] ----------------
__global__ __launch_bounds__(256) void k_red(const float* __restrict__ partials,
                                             float* __restrict__ sbuf, int nb) {
    int b0 = blockIdx.x * 32;
    int b1 = min(nb, b0 + 32);
    int t = threadIdx.x;
    float s0 = 0.f, s1 = 0.f;
    for (int b = b0; b < b1; ++b) {
        const float* row = partials + (size_t)b * 512;
        s0 += row[t];
        s1 += row[t + 256];
    }
    atomicAdd(&sbuf[t], s0);
    atomicAdd(&sbuf[t + 256], s1);
}

// ---------------- K6: mean_msg = ([s_src,s_dst,se] @ W)/E + mp_b ----------------
__global__ __launch_bounds__(256) void k_mm(const float* __restrict__ sbuf,
        const float* __restrict__ sum_attr, const float* __restrict__ w_edge,
        const float* __restrict__ b_edge, const float* __restrict__ W,
        const float* __restrict__ mpb, float* __restrict__ mean_msg, float Ef) {
    __shared__ float sc[384];
    __shared__ float mred[256];
    int t = threadIdx.x;
    if (t < 128) {
        sc[t]       = sbuf[t]       + sbuf[t + 128];
        sc[128 + t] = sbuf[256 + t] + sbuf[384 + t];
        float se = Ef * b_edge[t];
#pragma unroll
        for (int k = 0; k < EDIM; ++k) se = fmaf(sum_attr[k], w_edge[k * HDIM + t], se);
        sc[256 + t] = se;
    }
    __syncthreads();
    int col = blockIdx.x * 16 + (t & 15);
    int rg = t >> 4;
    float acc = 0.f;
#pragma unroll 4
    for (int r = rg * 24; r < rg * 24 + 24; ++r)
        acc = fmaf(sc[r], W[r * HDIM + col], acc);
    mred[t] = acc;
    __syncthreads();
    if (t < 16) {
        float s = 0.f;
#pragma unroll
        for (int g = 0; g < 16; ++g) s += mred[g * 16 + t];
        mean_msg[blockIdx.x * 16 + t] = s / Ef + mpb[blockIdx.x * 16 + t];
    }
}

// ---------------- K7: fused layer-0: tiled LDS GEMM + LN + relu + weighted sums ----------------
__global__ __launch_bounds__(256) void k_upd0(
        const float* __restrict__ x, const float* __restrict__ w_node,
        const float* __restrict__ b_node, const float* __restrict__ mean_msg,
        const float* __restrict__ ln_g, const float* __restrict__ ln_b,
        const float* __restrict__ c_src, const float* __restrict__ c_dst,
        float* __restrict__ h, float* __restrict__ partials, int N, int ntiles) {
    __shared__ float wl[XDIM * HDIM];     // 33792 B
    __shared__ float xl[T0ROWS * XDIM];   // 16896 B (reused as reduce buffer at end)
    int t = threadIdx.x;
    int cg = t & 31, rg = t >> 5;         // cg: 32 col-groups, rg: 8 row-groups
    int c0 = cg * 4;
    for (int i = t; i < XDIM * HDIM / 2; i += 256)
        ((float2*)wl)[i] = ((const float2*)w_node)[i];
    float4 b4 = *(const float4*)(b_node + c0);
    float4 m4 = *(const float4*)(mean_msg + c0);
    float4 bm = {b4.x + m4.x, b4.y + m4.y, b4.z + m4.z, b4.w + m4.w};
    float4 g4  = *(const float4*)(ln_g + c0);
    float4 lb4 = *(const float4*)(ln_b + c0);
    float4 accS = {0, 0, 0, 0}, accD = {0, 0, 0, 0};

    for (int tile = blockIdx.x; tile < ntiles; tile += gridDim.x) {
        int rowbase = tile * T0ROWS;
        const float* xg = x + (size_t)rowbase * XDIM;
        int vr = min(T0ROWS, N - rowbase);
        int lim = vr * XDIM;
        __syncthreads();   // previous tile's xl reads (and initial wl stage) complete
        for (int i = t; i < T0ROWS * XDIM / 2; i += 256) {
            int e = i * 2;
            float2 vv;
            if (e + 2 <= lim) vv = *(const float2*)(xg + e);
            else { vv.x = (e < lim) ? xg[e] : 0.f; vv.y = (e + 1 < lim) ? xg[e + 1] : 0.f; }
            ((float2*)xl)[i] = vv;
        }
        __syncthreads();

        float4 acc[8];
#pragma unroll
        for (int j = 0; j < 8; ++j) acc[j] = bm;
        const float* xrow = xl + rg * 8 * XDIM;
#pragma unroll 6
        for (int k = 0; k < XDIM; ++k) {
            float4 wv = *(const float4*)(wl + k * HDIM + c0);
#pragma unroll
            for (int j = 0; j < 8; ++j) {
                float xv = xrow[j * XDIM + k];
                acc[j].x = fmaf(xv, wv.x, acc[j].x);
                acc[j].y = fmaf(xv, wv.y, acc[j].y);
                acc[j].z = fmaf(xv, wv.z, acc[j].z);
                acc[j].w = fmaf(xv, wv.w, acc[j].w);
            }
        }
        // c arrays padded & zeroed past N -> unguarded vector loads safe
        float4 csA = *(const float4*)(c_src + rowbase + rg * 8);
        float4 csB = *(const float4*)(c_src + rowbase + rg * 8 + 4);
        float4 cdA = *(const float4*)(c_dst + rowbase + rg * 8);
        float4 cdB = *(const float4*)(c_dst + rowbase + rg * 8 + 4);
        float csArr[8] = {csA.x, csA.y, csA.z, csA.w, csB.x, csB.y, csB.z, csB.w};
        float cdArr[8] = {cdA.x, cdA.y, cdA.z, cdA.w, cdB.x, cdB.y, cdB.z, cdB.w};
#pragma unroll
        for (int j = 0; j < 8; ++j) {
            float4 a = acc[j];
            float s = a.x + a.y + a.z + a.w;
#pragma unroll
            for (int m = 16; m; m >>= 1) s += __shfl_xor(s, m);   // 32-lane col-group
            float mu = s * (1.0f / HDIM);
            float d0 = a.x - mu, d1 = a.y - mu, d2 = a.z - mu, d3 = a.w - mu;
            float q = d0 * d0 + d1 * d1 + d2 * d2 + d3 * d3;
#pragma unroll
            for (int m = 16; m; m >>= 1) q += __shfl_xor(q, m);
            float rs = rsqrtf(q * (1.0f / HDIM) + LN_EPS);
            float4 o;
            o.x = fmaxf(0.f, fmaf(d0 * rs, g4.x, lb4.x));
            o.y = fmaxf(0.f, fmaf(d1 * rs, g4.y, lb4.y));
            o.z = fmaxf(0.f, fmaf(d2 * rs, g4.z, lb4.z));
            o.w = fmaxf(0.f, fmaf(d3 * rs, g4.w, lb4.w));
            int row = rowbase + rg * 8 + j;
            if (row < N)
                *(float4*)(h + (size_t)row * HDIM + c0) = o;
            float cs = csArr[j], cd = cdArr[j];
            accS.x = fmaf(cs, o.x, accS.x); accS.y = fmaf(cs, o.y, accS.y);
            accS.z = fmaf(cs, o.z, accS.z); accS.w = fmaf(cs, o.w, accS.w);
            accD.x = fmaf(cd, o.x, accD.x); accD.y = fmaf(cd, o.y, accD.y);
            accD.z = fmaf(cd, o.z, accD.z); accD.w = fmaf(cd, o.w, accD.w);
        }
    }
    // block-level reduce of accS/accD across the 8 row-groups (reuse xl)
    __syncthreads();
    float* red = xl;   // needs 2048 floats <= 4224
    *(float4*)(red + rg * HDIM + c0) = accS;
    *(float4*)(red + 1024 + rg * HDIM + c0) = accD;
    __syncthreads();
    if (t < 128) {
        float s = 0.f, d = 0.f;
#pragma unroll
        for (int gi = 0; gi < 8; ++gi) {
            s += red[gi * HDIM + t];
            d += red[1024 + gi * HDIM + t];
        }
        float* row = partials + (size_t)blockIdx.x * 512;
        row[t] = s;        row[t + 128] = 0.f;
        row[t + 256] = d;  row[t + 384] = 0.f;
    }
}

// ---------------- LN helper for k_update (full-wave reduce, 2 cols/lane) ----------------
__device__ __forceinline__ float2 ln_relu2(float2 v, float2 g, float2 bb) {
    float s = v.x + v.y;
#pragma unroll
    for (int m = 32; m; m >>= 1) s += __shfl_xor(s, m);
    float mu = s * (1.0f / HDIM);
    float dx = v.x - mu, dy = v.y - mu;
    float q = dx * dx + dy * dy;
#pragma unroll
    for (int m = 32; m; m >>= 1) q += __shfl_xor(q, m);
    float rs = rsqrtf(q * (1.0f / HDIM) + LN_EPS);
    float2 o;
    o.x = fmaxf(0.f, fmaf(dx * rs, g.x, bb.x));
    o.y = fmaxf(0.f, fmaf(dy * rs, g.y, bb.y));
    return o;
}

// ---------------- K8: h = relu(LN(h + mm)); next-layer sums or pooling (4-row ILP) ----------------
template <int LAST>
__global__ __launch_bounds__(256) void k_update(
        float* __restrict__ h, const float* __restrict__ mean_msg,
        const float* __restrict__ ln_g, const float* __restrict__ ln_b,
        const float* __restrict__ c_src, const float* __restrict__ c_dst,
        const int* __restrict__ batch, float* __restrict__ partials,
        float* __restrict__ pooled, int N, int cpb) {
    int t = threadIdx.x;
    int lane = t & 63, w = t >> 6;
    int c0 = lane * 2;
    float2 mm = *(const float2*)(mean_msg + c0);
    float2 g  = *(const float2*)(ln_g + c0);
    float2 bb = *(const float2*)(ln_b + c0);
    int start = blockIdx.x * cpb;
    int end = min(N, start + cpb);
    int spw = (cpb + 3) >> 2;
    int ns = start + w * spw;
    int ne = min(end, ns + spw);
    float2 accS = {0.f, 0.f}, accD = {0.f, 0.f}, accP = {0.f, 0.f};
    int cur_g = -1;
    int n = ns;
    for (; n + 4 <= ne; n += 4) {
        float2 v0 = *(const float2*)(h + (size_t)(n    ) * HDIM + c0);
        float2 v1 = *(const float2*)(h + (size_t)(n + 1) * HDIM + c0);
        float2 v2 = *(const float2*)(h + (size_t)(n + 2) * HDIM + c0);
        float2 v3 = *(const float2*)(h + (size_t)(n + 3) * HDIM + c0);
        v0.x += mm.x; v0.y += mm.y;  v1.x += mm.x; v1.y += mm.y;
        v2.x += mm.x; v2.y += mm.y;  v3.x += mm.x; v3.y += mm.y;
        float2 o0 = ln_relu2(v0, g, bb);
        float2 o1 = ln_relu2(v1, g, bb);
        float2 o2 = ln_relu2(v2, g, bb);
        float2 o3 = ln_relu2(v3, g, bb);
        if (LAST) {
            int gi[4] = {batch[n], batch[n + 1], batch[n + 2], batch[n + 3]};
            float2 oo[4] = {o0, o1, o2, o3};
#pragma unroll
            for (int r = 0; r < 4; ++r) {
                if (gi[r] != cur_g) {
                    if (cur_g >= 0) {
                        atomicAdd(&pooled[cur_g * HDIM + c0],     accP.x);
                        atomicAdd(&pooled[cur_g * HDIM + c0 + 1], accP.y);
                    }
                    accP.x = 0.f; accP.y = 0.f;
                    cur_g = gi[r];
                }
                accP.x += oo[r].x; accP.y += oo[r].y;
            }
        } else {
            *(float2*)(h + (size_t)(n    ) * HDIM + c0) = o0;
            *(float2*)(h + (size_t)(n + 1) * HDIM + c0) = o1;
            *(float2*)(h + (size_t)(n + 2) * HDIM + c0) = o2;
            *(float2*)(h + (size_t)(n + 3) * HDIM + c0) = o3;
            float cs0 = c_src[n], cs1 = c_src[n+1], cs2 = c_src[n+2], cs3 = c_src[n+3];
            float cd0 = c_dst[n], cd1 = c_dst[n+1], cd2 = c_dst[n+2], cd3 = c_dst[n+3];
            accS.x = fmaf(cs0, o0.x, accS.x); accS.y = fmaf(cs0, o0.y, accS.y);
            accS.x = fmaf(cs1, o1.x, accS.x); accS.y = fmaf(cs1, o1.y, accS.y);
            accS.x = fmaf(cs2, o2.x, accS.x); accS.y = fmaf(cs2, o2.y, accS.y);
            accS.x = fmaf(cs3, o3.x, accS.x); accS.y = fmaf(cs3, o3.y, accS.y);
            accD.x = fmaf(cd0, o0.x, accD.x); accD.y = fmaf(cd0, o0.y, accD.y);
            accD.x = fmaf(cd1, o1.x, accD.x); accD.y = fmaf(cd1, o1.y, accD.y);
            accD.x = fmaf(cd2, o2.x, accD.x); accD.y = fmaf(cd2, o2.y, accD.y);
            accD.x = fmaf(cd3, o3.x, accD.x); accD.y = fmaf(cd3, o3.y, accD.y);
        }
    }
    for (; n < ne; ++n) {
        float2 v = *(const float2*)(h + (size_t)n * HDIM + c0);
        v.x += mm.x; v.y += mm.y;
        float2 o = ln_relu2(v, g, bb);
        if (LAST) {
            int gg = batch[n];
            if (gg != cur_g) {
                if (cur_g >= 0) {
                    atomicAdd(&pooled[cur_g * HDIM + c0],     accP.x);
                    atomicAdd(&pooled[cur_g * HDIM + c0 + 1], accP.y);
                }
                accP.x = 0.f; accP.y = 0.f;
                cur_g = gg;
            }
            accP.x += o.x; accP.y += o.y;
        } else {
            *(float2*)(h + (size_t)n * HDIM + c0) = o;
            float cs = c_src[n], cd = c_dst[n];
            accS.x = fmaf(cs, o.x, accS.x); accS.y = fmaf(cs, o.y, accS.y);
            accD.x = fmaf(cd, o.x, accD.x); accD.y = fmaf(cd, o.y, accD.y);
        }
    }
    if (LAST) {
        if (cur_g >= 0) {
            atomicAdd(&pooled[cur_g * HDIM + c0],     accP.x);
            atomicAdd(&pooled[cur_g * HDIM + c0 + 1], accP.y);
        }
    } else {
        __shared__ float sb[HDIM], db[HDIM];
        if (t < HDIM) { sb[t] = 0.f; db[t] = 0.f; }
        __syncthreads();
        atomicAdd(&sb[c0], accS.x); atomicAdd(&sb[c0 + 1], accS.y);
        atomicAdd(&db[c0], accD.x); atomicAdd(&db[c0 + 1], accD.y);
        __syncthreads();
        float* row = partials + (size_t)blockIdx.x * 512;
        if (t < 128) {
            row[t] = sb[t];        row[t + 128] = 0.f;
            row[t + 256] = db[t];  row[t + 384] = 0.f;
        }
    }
}

// ---------------- K9: out = (pooled / max(cnt,1)) @ w_out + b_out ----------------
__global__ __launch_bounds__(128) void k_out(const float* __restrict__ pooled,
        const int* __restrict__ batch, const float* __restrict__ w_out,
        const float* __restrict__ b_out, float* __restrict__ out, int N) {
    int gph = blockIdx.x;
    int t = threadIdx.x;
    __shared__ float p[HDIM];
    __shared__ int cntS;
    if (t == 0) {
        int lo = 0, hi = N;
        while (lo < hi) { int mid = (lo + hi) >> 1; if (batch[mid] < gph) lo = mid + 1; else hi = mid; }
        int lo2 = lo, hi2 = N;
        while (lo2 < hi2) { int mid = (lo2 + hi2) >> 1; if (batch[mid] <= gph) lo2 = mid + 1; else hi2 = mid; }
        cntS = lo2 - lo;
    }
    __syncthreads();
    float inv = 1.0f / fmaxf((float)cntS, 1.0f);
    p[t] = pooled[gph * HDIM + t] * inv;
    __syncthreads();
    float acc = b_out[t];
#pragma unroll 8
    for (int k = 0; k < HDIM; ++k) acc = fmaf(p[k], w_out[k * HDIM + t], acc);
    out[gph * HDIM + t] = acc;
}

extern "C" void kernel_launch(void* const* d_in, const int* in_sizes, int n_in,
                              void* d_out, int out_size, void* d_ws, size_t ws_size,
                              hipStream_t stream) {
    const float* x      = (const float*)d_in[0];
    const int*   ei     = (const int*)d_in[1];
    const float* ea     = (const float*)d_in[2];
    const int*   batch  = (const int*)d_in[3];
    const float* w_node = (const float*)d_in[4];
    const float* b_node = (const float*)d_in[5];
    const float* w_edge = (const float*)d_in[6];
    const float* b_edge = (const float*)d_in[7];
    const float* mp_w   = (const float*)d_in[8];
    const float* mp_b   = (const float*)d_in[9];
    const float* ln_g   = (const float*)d_in[10];
    const float* ln_b   = (const float*)d_in[11];
    const float* w_out  = (const float*)d_in[12];
    const float* b_out  = (const float*)d_in[13];
    float* out = (float*)d_out;
    int N = in_sizes[3];
    int E = in_sizes[2] / EDIM;
    float Ef = (float)E;
    int ntiles = (N + T0ROWS - 1) / T0ROWS;

    float* ws = (float*)d_ws;
    size_t off = 0;
    float* h        = ws + off; off += (size_t)N * HDIM;
    float* partials = ws + off; off += (size_t)1024 * 512;
    float* mean_msg = ws + off; off += 128;
    // ---- accumulator region (contiguous, zeroed every call) ----
    float* acc0     = ws + off;
    float* c_src    = ws + off; off += N + 64;   // padded: tiles read past N
    float* c_dst    = ws + off; off += N + 64;
    float* sum_attr = ws + off; off += 8;
    float* xs       = ws + off; off += 136;
    float* sbuf0    = ws + off; off += 512;
    float* sbuf1    = ws + off; off += 512;
    float* sbuf2    = ws + off; off += 512;
    float* pooled   = ws + off; off += NGRAPHS * HDIM;
    size_t zero_count = (size_t)(ws + off - acc0);
    hipMemsetAsync(acc0, 0, zero_count * sizeof(float), stream);

    k_hist<<<(E + 255) / 256, 256, 0, stream>>>(ei, c_src, c_dst, E);
    k_edgesum<<<128, 256, 0, stream>>>(ea, sum_attr, E);
    k_xsum<<<256, 256, 0, stream>>>(x, c_src, c_dst, xs, N, ntiles);
    k_s0<<<1, 256, 0, stream>>>(xs, w_node, b_node, sbuf0, Ef);

    const int NB0 = 768;   // k_upd0 grid (3 blocks/CU at 50KB LDS)
    const int NB = 1024;
    int cpb = (N + NB - 1) / NB;

    // layer 0
    k_mm<<<8, 256, 0, stream>>>(sbuf0, sum_attr, w_edge, b_edge,
                                mp_w, mp_b, mean_msg, Ef);
    k_upd0<<<NB0, 256, 0, stream>>>(x, w_node, b_node, mean_msg, ln_g, ln_b,
                                    c_src, c_dst, h, partials, N, ntiles);
    // layer 1
    k_red<<<(NB0 + 31) / 32, 256, 0, stream>>>(partials, sbuf1, NB0);
    k_mm<<<8, 256, 0, stream>>>(sbuf1, sum_attr, w_edge, b_edge,
                                mp_w + (size_t)1 * 384 * HDIM,
                                mp_b + (size_t)1 * HDIM, mean_msg, Ef);
    k_update<0><<<NB, 256, 0, stream>>>(h, mean_msg, ln_g, ln_b, c_src, c_dst,
                                        batch, partials, pooled, N, cpb);
    // layer 2
    k_red<<<NB / 32, 256, 0, stream>>>(partials, sbuf2, NB);
    k_mm<<<8, 256, 0, stream>>>(sbuf2, sum_attr, w_edge, b_edge,
                                mp_w + (size_t)2 * 384 * HDIM,
                                mp_b + (size_t)2 * HDIM, mean_msg, Ef);
    k_update<1><<<NB, 256, 0, stream>>>(h, mean_msg, ln_g, ln_b, c_src, c_dst,
                                        batch, partials, pooled, N, cpb);

    k_out<<<NGRAPHS, HDIM, 0, stream>>>(pooled, batch, w_out, b_out, out, N);
}

// Round 4
// 257.098 us; speedup vs baseline: 1.3730x; 1.0755x over previous
//
#include <hip/hip_runtime.h>

#define HDIM 128
#define XDIM 66
#define EDIM 6
#define NGRAPHS 256
#define LN_EPS 1e-5f
#define T0ROWS 64

// ---------------- K1: degree histograms of edge_index (2 edges/thread) ----------------
__global__ void k_hist(const int* __restrict__ ei, float* __restrict__ c_src,
                       float* __restrict__ c_dst, int E) {
    int e2 = blockIdx.x * blockDim.x + threadIdx.x;
    int e0 = e2 * 2;
    if (e0 + 1 < E) {
        int2 s = *(const int2*)(ei + e0);
        int2 d = *(const int2*)(ei + E + e0);
        atomicAdd(&c_src[s.x], 1.0f);
        atomicAdd(&c_src[s.y], 1.0f);
        atomicAdd(&c_dst[d.x], 1.0f);
        atomicAdd(&c_dst[d.y], 1.0f);
    } else if (e0 < E) {
        atomicAdd(&c_src[ei[e0]], 1.0f);
        atomicAdd(&c_dst[ei[E + e0]], 1.0f);
    }
}

// ---------------- K2: column-sum of edge_attr (E,6) ----------------
__global__ __launch_bounds__(256) void k_edgesum(const float* __restrict__ ea,
                                                 float* __restrict__ sum_attr, int E) {
    int nchunk = E >> 1;
    float a0 = 0, a1 = 0, a2 = 0, a3 = 0, a4 = 0, a5 = 0;
    for (int c = blockIdx.x * blockDim.x + threadIdx.x; c < nchunk;
         c += gridDim.x * blockDim.x) {
        const float4* p = (const float4*)(ea + (size_t)c * 12);
        float4 v0 = p[0], v1 = p[1], v2 = p[2];
        a0 += v0.x + v1.z;  a1 += v0.y + v1.w;  a2 += v0.z + v2.x;
        a3 += v0.w + v2.y;  a4 += v1.x + v2.z;  a5 += v1.y + v2.w;
    }
#pragma unroll
    for (int m = 32; m; m >>= 1) {
        a0 += __shfl_xor(a0, m); a1 += __shfl_xor(a1, m); a2 += __shfl_xor(a2, m);
        a3 += __shfl_xor(a3, m); a4 += __shfl_xor(a4, m); a5 += __shfl_xor(a5, m);
    }
    __shared__ float sbuf[4][6];
    int lane = threadIdx.x & 63, w = threadIdx.x >> 6;
    if (lane == 0) {
        sbuf[w][0] = a0; sbuf[w][1] = a1; sbuf[w][2] = a2;
        sbuf[w][3] = a3; sbuf[w][4] = a4; sbuf[w][5] = a5;
    }
    __syncthreads();
    if (threadIdx.x < 6) {
        float s = sbuf[0][threadIdx.x] + sbuf[1][threadIdx.x] +
                  sbuf[2][threadIdx.x] + sbuf[3][threadIdx.x];
        atomicAdd(&sum_attr[threadIdx.x], s);
    }
    if (blockIdx.x == 0 && threadIdx.x < 6 && (E & 1))
        atomicAdd(&sum_attr[threadIdx.x], ea[(size_t)(E - 1) * 6 + threadIdx.x]);
}

// ---------------- K3: weighted column sums of x (4-row ILP, no shfl in loop) ----------------
__global__ __launch_bounds__(256) void k_xsum(const float* __restrict__ x,
        const float* __restrict__ c_src, const float* __restrict__ c_dst,
        float* __restrict__ xs, int N) {
    int lane = threadIdx.x & 63, w = threadIdx.x >> 6;
    int wid = blockIdx.x * 4 + w, nw = gridDim.x * 4;
    float as0 = 0, ad0 = 0, as1 = 0, ad1 = 0;
    int Q = N >> 2;
    for (int q = wid; q < Q; q += nw) {
        int n = q * 4;
        const float* xr = x + (size_t)n * XDIM;
        // 4 independent coalesced row loads
        float x0 = xr[lane];
        float x1 = xr[XDIM + lane];
        float x2 = xr[2 * XDIM + lane];
        float x3 = xr[3 * XDIM + lane];
        float4 cs = *(const float4*)(c_src + n);   // same-address broadcast
        float4 cd = *(const float4*)(c_dst + n);
        as0 = fmaf(cs.x, x0, as0); as0 = fmaf(cs.y, x1, as0);
        as0 = fmaf(cs.z, x2, as0); as0 = fmaf(cs.w, x3, as0);
        ad0 = fmaf(cd.x, x0, ad0); ad0 = fmaf(cd.y, x1, ad0);
        ad0 = fmaf(cd.z, x2, ad0); ad0 = fmaf(cd.w, x3, ad0);
        if (lane < 2) {
            float e0 = xr[64 + lane];
            float e1 = xr[XDIM + 64 + lane];
            float e2 = xr[2 * XDIM + 64 + lane];
            float e3 = xr[3 * XDIM + 64 + lane];
            as1 = fmaf(cs.x, e0, as1); as1 = fmaf(cs.y, e1, as1);
            as1 = fmaf(cs.z, e2, as1); as1 = fmaf(cs.w, e3, as1);
            ad1 = fmaf(cd.x, e0, ad1); ad1 = fmaf(cd.y, e1, ad1);
            ad1 = fmaf(cd.z, e2, ad1); ad1 = fmaf(cd.w, e3, ad1);
        }
    }
    if (wid == 0) {   // tail rows
        for (int n = Q * 4; n < N; ++n) {
            const float* xr = x + (size_t)n * XDIM;
            float cs = c_src[n], cd = c_dst[n];
            float xv = xr[lane];
            as0 = fmaf(cs, xv, as0);
            ad0 = fmaf(cd, xv, ad0);
            if (lane < 2) {
                float xe = xr[64 + lane];
                as1 = fmaf(cs, xe, as1);
                ad1 = fmaf(cd, xe, ad1);
            }
        }
    }
    __shared__ float redS[4][XDIM], redD[4][XDIM];
    redS[w][lane] = as0;  redD[w][lane] = ad0;
    if (lane < 2) { redS[w][64 + lane] = as1;  redD[w][64 + lane] = ad1; }
    __syncthreads();
    int t = threadIdx.x;
    if (t < XDIM) {
        atomicAdd(&xs[t],        redS[0][t] + redS[1][t] + redS[2][t] + redS[3][t]);
        atomicAdd(&xs[XDIM + t], redD[0][t] + redD[1][t] + redD[2][t] + redD[3][t]);
    }
}

// ---------------- K6: mean_msg = ([s_src,s_dst,se] @ W)/E + mp_b ----------------
// FIRST=1: sv = xs[136]; s_src/s_dst computed as xs @ w_node + E*b_node.
// FIRST=0: sv = sbuf[512] from k_red.
template <int FIRST>
__global__ __launch_bounds__(256) void k_mm(const float* __restrict__ sv,
        const float* __restrict__ sum_attr, const float* __restrict__ w_edge,
        const float* __restrict__ b_edge, const float* __restrict__ W,
        const float* __restrict__ mpb, float* __restrict__ mean_msg, float Ef,
        const float* __restrict__ w_node, const float* __restrict__ b_node) {
    __shared__ float sc[384];
    __shared__ float mred[256];
    int t = threadIdx.x;
    if (t < 128) {
        float ssrc, sdst;
        if (FIRST) {
            ssrc = Ef * b_node[t];
            sdst = ssrc;
#pragma unroll
            for (int k = 0; k < XDIM; ++k) {
                float wv = w_node[k * HDIM + t];
                ssrc = fmaf(sv[k], wv, ssrc);
                sdst = fmaf(sv[XDIM + k], wv, sdst);
            }
        } else {
            ssrc = sv[t] + sv[t + 128];
            sdst = sv[256 + t] + sv[384 + t];
        }
        sc[t] = ssrc;
        sc[128 + t] = sdst;
        float se = Ef * b_edge[t];
#pragma unroll
        for (int k = 0; k < EDIM; ++k) se = fmaf(sum_attr[k], w_edge[k * HDIM + t], se);
        sc[256 + t] = se;
    }
    __syncthreads();
    int col = blockIdx.x * 16 + (t & 15);
    int rg = t >> 4;
    float acc = 0.f;
#pragma unroll 4
    for (int r = rg * 24; r < rg * 24 + 24; ++r)
        acc = fmaf(sc[r], W[r * HDIM + col], acc);
    mred[t] = acc;
    __syncthreads();
    if (t < 16) {
        float s = 0.f;
#pragma unroll
        for (int g = 0; g < 16; ++g) s += mred[g * 16 + t];
        mean_msg[blockIdx.x * 16 + t] = s / Ef + mpb[blockIdx.x * 16 + t];
    }
}

// ---------------- K5: reduce per-block partials -> sbuf[512] ----------------
__global__ __launch_bounds__(256) void k_red(const float* __restrict__ partials,
                                             float* __restrict__ sbuf, int nb) {
    int b0 = blockIdx.x * 32;
    int b1 = min(nb, b0 + 32);
    int t = threadIdx.x;
    float s0 = 0.f, s1 = 0.f;
    for (int b = b0; b < b1; ++b) {
        const float* row = partials + (size_t)b * 512;
        s0 += row[t];
        s1 += row[t + 256];
    }
    atomicAdd(&sbuf[t], s0);
    atomicAdd(&sbuf[t + 256], s1);
}

// ---------------- K7: fused layer-0: tiled LDS GEMM + LN + relu + weighted sums ----------------
__global__ __launch_bounds__(256) void k_upd0(
        const float* __restrict__ x, const float* __restrict__ w_node,
        const float* __restrict__ b_node, const float* __restrict__ mean_msg,
        const float* __restrict__ ln_g, const float* __restrict__ ln_b,
        const float* __restrict__ c_src, const float* __restrict__ c_dst,
        float* __restrict__ h, float* __restrict__ partials, int N, int ntiles) {
    __shared__ float wl[XDIM * HDIM];     // 33792 B
    __shared__ float xl[T0ROWS * XDIM];   // 16896 B (reused as reduce buffer at end)
    int t = threadIdx.x;
    int cg = t & 31, rg = t >> 5;
    int c0 = cg * 4;
    for (int i = t; i < XDIM * HDIM / 2; i += 256)
        ((float2*)wl)[i] = ((const float2*)w_node)[i];
    float4 b4 = *(const float4*)(b_node + c0);
    float4 m4 = *(const float4*)(mean_msg + c0);
    float4 bm = {b4.x + m4.x, b4.y + m4.y, b4.z + m4.z, b4.w + m4.w};
    float4 g4  = *(const float4*)(ln_g + c0);
    float4 lb4 = *(const float4*)(ln_b + c0);
    float4 accS = {0, 0, 0, 0}, accD = {0, 0, 0, 0};

    for (int tile = blockIdx.x; tile < ntiles; tile += gridDim.x) {
        int rowbase = tile * T0ROWS;
        const float* xg = x + (size_t)rowbase * XDIM;
        int vr = min(T0ROWS, N - rowbase);
        int lim = vr * XDIM;
        __syncthreads();
        for (int i = t; i < T0ROWS * XDIM / 2; i += 256) {
            int e = i * 2;
            float2 vv;
            if (e + 2 <= lim) vv = *(const float2*)(xg + e);
            else { vv.x = (e < lim) ? xg[e] : 0.f; vv.y = (e + 1 < lim) ? xg[e + 1] : 0.f; }
            ((float2*)xl)[i] = vv;
        }
        __syncthreads();

        float4 acc[8];
#pragma unroll
        for (int j = 0; j < 8; ++j) acc[j] = bm;
        const float* xrow = xl + rg * 8 * XDIM;
#pragma unroll 6
        for (int k = 0; k < XDIM; ++k) {
            float4 wv = *(const float4*)(wl + k * HDIM + c0);
#pragma unroll
            for (int j = 0; j < 8; ++j) {
                float xv = xrow[j * XDIM + k];
                acc[j].x = fmaf(xv, wv.x, acc[j].x);
                acc[j].y = fmaf(xv, wv.y, acc[j].y);
                acc[j].z = fmaf(xv, wv.z, acc[j].z);
                acc[j].w = fmaf(xv, wv.w, acc[j].w);
            }
        }
        float4 csA = *(const float4*)(c_src + rowbase + rg * 8);
        float4 csB = *(const float4*)(c_src + rowbase + rg * 8 + 4);
        float4 cdA = *(const float4*)(c_dst + rowbase + rg * 8);
        float4 cdB = *(const float4*)(c_dst + rowbase + rg * 8 + 4);
        float csArr[8] = {csA.x, csA.y, csA.z, csA.w, csB.x, csB.y, csB.z, csB.w};
        float cdArr[8] = {cdA.x, cdA.y, cdA.z, cdA.w, cdB.x, cdB.y, cdB.z, cdB.w};
#pragma unroll
        for (int j = 0; j < 8; ++j) {
            float4 a = acc[j];
            float s = a.x + a.y + a.z + a.w;
#pragma unroll
            for (int m = 16; m; m >>= 1) s += __shfl_xor(s, m);
            float mu = s * (1.0f / HDIM);
            float d0 = a.x - mu, d1 = a.y - mu, d2 = a.z - mu, d3 = a.w - mu;
            float q = d0 * d0 + d1 * d1 + d2 * d2 + d3 * d3;
#pragma unroll
            for (int m = 16; m; m >>= 1) q += __shfl_xor(q, m);
            float rs = rsqrtf(q * (1.0f / HDIM) + LN_EPS);
            float4 o;
            o.x = fmaxf(0.f, fmaf(d0 * rs, g4.x, lb4.x));
            o.y = fmaxf(0.f, fmaf(d1 * rs, g4.y, lb4.y));
            o.z = fmaxf(0.f, fmaf(d2 * rs, g4.z, lb4.z));
            o.w = fmaxf(0.f, fmaf(d3 * rs, g4.w, lb4.w));
            int row = rowbase + rg * 8 + j;
            if (row < N)
                *(float4*)(h + (size_t)row * HDIM + c0) = o;
            float cs = csArr[j], cd = cdArr[j];
            accS.x = fmaf(cs, o.x, accS.x); accS.y = fmaf(cs, o.y, accS.y);
            accS.z = fmaf(cs, o.z, accS.z); accS.w = fmaf(cs, o.w, accS.w);
            accD.x = fmaf(cd, o.x, accD.x); accD.y = fmaf(cd, o.y, accD.y);
            accD.z = fmaf(cd, o.z, accD.z); accD.w = fmaf(cd, o.w, accD.w);
        }
    }
    __syncthreads();
    float* red = xl;
    *(float4*)(red + rg * HDIM + c0) = accS;
    *(float4*)(red + 1024 + rg * HDIM + c0) = accD;
    __syncthreads();
    if (t < 128) {
        float s = 0.f, d = 0.f;
#pragma unroll
        for (int gi = 0; gi < 8; ++gi) {
            s += red[gi * HDIM + t];
            d += red[1024 + gi * HDIM + t];
        }
        float* row = partials + (size_t)blockIdx.x * 512;
        row[t] = s;        row[t + 128] = 0.f;
        row[t + 256] = d;  row[t + 384] = 0.f;
    }
}

// ---------------- LN helper ----------------
__device__ __forceinline__ float2 ln_relu2(float2 v, float2 g, float2 bb) {
    float s = v.x + v.y;
#pragma unroll
    for (int m = 32; m; m >>= 1) s += __shfl_xor(s, m);
    float mu = s * (1.0f / HDIM);
    float dx = v.x - mu, dy = v.y - mu;
    float q = dx * dx + dy * dy;
#pragma unroll
    for (int m = 32; m; m >>= 1) q += __shfl_xor(q, m);
    float rs = rsqrtf(q * (1.0f / HDIM) + LN_EPS);
    float2 o;
    o.x = fmaxf(0.f, fmaf(dx * rs, g.x, bb.x));
    o.y = fmaxf(0.f, fmaf(dy * rs, g.y, bb.y));
    return o;
}

// ---------------- K8: h = relu(LN(h + mm)); next-layer sums or pooling ----------------
template <int LAST>
__global__ __launch_bounds__(256) void k_update(
        float* __restrict__ h, const float* __restrict__ mean_msg,
        const float* __restrict__ ln_g, const float* __restrict__ ln_b,
        const float* __restrict__ c_src, const float* __restrict__ c_dst,
        const int* __restrict__ batch, float* __restrict__ partials,
        float* __restrict__ pooled, int N, int cpb) {
    int t = threadIdx.x;
    int lane = t & 63, w = t >> 6;
    int c0 = lane * 2;
    float2 mm = *(const float2*)(mean_msg + c0);
    float2 g  = *(const float2*)(ln_g + c0);
    float2 bb = *(const float2*)(ln_b + c0);
    int start = blockIdx.x * cpb;
    int end = min(N, start + cpb);
    int spw = (cpb + 3) >> 2;
    int ns = start + w * spw;
    int ne = min(end, ns + spw);
    float2 accS = {0.f, 0.f}, accD = {0.f, 0.f}, accP = {0.f, 0.f};
    int cur_g = -1;
    int n = ns;
    for (; n + 4 <= ne; n += 4) {
        float2 v0 = *(const float2*)(h + (size_t)(n    ) * HDIM + c0);
        float2 v1 = *(const float2*)(h + (size_t)(n + 1) * HDIM + c0);
        float2 v2 = *(const float2*)(h + (size_t)(n + 2) * HDIM + c0);
        float2 v3 = *(const float2*)(h + (size_t)(n + 3) * HDIM + c0);
        v0.x += mm.x; v0.y += mm.y;  v1.x += mm.x; v1.y += mm.y;
        v2.x += mm.x; v2.y += mm.y;  v3.x += mm.x; v3.y += mm.y;
        float2 o0 = ln_relu2(v0, g, bb);
        float2 o1 = ln_relu2(v1, g, bb);
        float2 o2 = ln_relu2(v2, g, bb);
        float2 o3 = ln_relu2(v3, g, bb);
        if (LAST) {
            int gi[4] = {batch[n], batch[n + 1], batch[n + 2], batch[n + 3]};
            float2 oo[4] = {o0, o1, o2, o3};
#pragma unroll
            for (int r = 0; r < 4; ++r) {
                if (gi[r] != cur_g) {
                    if (cur_g >= 0) {
                        atomicAdd(&pooled[cur_g * HDIM + c0],     accP.x);
                        atomicAdd(&pooled[cur_g * HDIM + c0 + 1], accP.y);
                    }
                    accP.x = 0.f; accP.y = 0.f;
                    cur_g = gi[r];
                }
                accP.x += oo[r].x; accP.y += oo[r].y;
            }
        } else {
            *(float2*)(h + (size_t)(n    ) * HDIM + c0) = o0;
            *(float2*)(h + (size_t)(n + 1) * HDIM + c0) = o1;
            *(float2*)(h + (size_t)(n + 2) * HDIM + c0) = o2;
            *(float2*)(h + (size_t)(n + 3) * HDIM + c0) = o3;
            float cs0 = c_src[n], cs1 = c_src[n+1], cs2 = c_src[n+2], cs3 = c_src[n+3];
            float cd0 = c_dst[n], cd1 = c_dst[n+1], cd2 = c_dst[n+2], cd3 = c_dst[n+3];
            accS.x = fmaf(cs0, o0.x, accS.x); accS.y = fmaf(cs0, o0.y, accS.y);
            accS.x = fmaf(cs1, o1.x, accS.x); accS.y = fmaf(cs1, o1.y, accS.y);
            accS.x = fmaf(cs2, o2.x, accS.x); accS.y = fmaf(cs2, o2.y, accS.y);
            accS.x = fmaf(cs3, o3.x, accS.x); accS.y = fmaf(cs3, o3.y, accS.y);
            accD.x = fmaf(cd0, o0.x, accD.x); accD.y = fmaf(cd0, o0.y, accD.y);
            accD.x = fmaf(cd1, o1.x, accD.x); accD.y = fmaf(cd1, o1.y, accD.y);
            accD.x = fmaf(cd2, o2.x, accD.x); accD.y = fmaf(cd2, o2.y, accD.y);
            accD.x = fmaf(cd3, o3.x, accD.x); accD.y = fmaf(cd3, o3.y, accD.y);
        }
    }
    for (; n < ne; ++n) {
        float2 v = *(const float2*)(h + (size_t)n * HDIM + c0);
        v.x += mm.x; v.y += mm.y;
        float2 o = ln_relu2(v, g, bb);
        if (LAST) {
            int gg = batch[n];
            if (gg != cur_g) {
                if (cur_g >= 0) {
                    atomicAdd(&pooled[cur_g * HDIM + c0],     accP.x);
                    atomicAdd(&pooled[cur_g * HDIM + c0 + 1], accP.y);
                }
                accP.x = 0.f; accP.y = 0.f;
                cur_g = gg;
            }
            accP.x += o.x; accP.y += o.y;
        } else {
            *(float2*)(h + (size_t)n * HDIM + c0) = o;
            float cs = c_src[n], cd = c_dst[n];
            accS.x = fmaf(cs, o.x, accS.x); accS.y = fmaf(cs, o.y, accS.y);
            accD.x = fmaf(cd, o.x, accD.x); accD.y = fmaf(cd, o.y, accD.y);
        }
    }
    if (LAST) {
        if (cur_g >= 0) {
            atomicAdd(&pooled[cur_g * HDIM + c0],     accP.x);
            atomicAdd(&pooled[cur_g * HDIM + c0 + 1], accP.y);
        }
    } else {
        __shared__ float sb[HDIM], db[HDIM];
        if (t < HDIM) { sb[t] = 0.f; db[t] = 0.f; }
        __syncthreads();
        atomicAdd(&sb[c0], accS.x); atomicAdd(&sb[c0 + 1], accS.y);
        atomicAdd(&db[c0], accD.x); atomicAdd(&db[c0 + 1], accD.y);
        __syncthreads();
        float* row = partials + (size_t)blockIdx.x * 512;
        if (t < 128) {
            row[t] = sb[t];        row[t + 128] = 0.f;
            row[t + 256] = db[t];  row[t + 384] = 0.f;
        }
    }
}

// ---------------- K9: out = (pooled / max(cnt,1)) @ w_out + b_out ----------------
__global__ __launch_bounds__(128) void k_out(const float* __restrict__ pooled,
        const int* __restrict__ batch, const float* __restrict__ w_out,
        const float* __restrict__ b_out, float* __restrict__ out, int N) {
    int gph = blockIdx.x;
    int t = threadIdx.x;
    __shared__ float p[HDIM];
    __shared__ int cntS;
    if (t == 0) {
        int lo = 0, hi = N;
        while (lo < hi) { int mid = (lo + hi) >> 1; if (batch[mid] < gph) lo = mid + 1; else hi = mid; }
        int lo2 = lo, hi2 = N;
        while (lo2 < hi2) { int mid = (lo2 + hi2) >> 1; if (batch[mid] <= gph) lo2 = mid + 1; else hi2 = mid; }
        cntS = lo2 - lo;
    }
    __syncthreads();
    float inv = 1.0f / fmaxf((float)cntS, 1.0f);
    p[t] = pooled[gph * HDIM + t] * inv;
    __syncthreads();
    float acc = b_out[t];
#pragma unroll 8
    for (int k = 0; k < HDIM; ++k) acc = fmaf(p[k], w_out[k * HDIM + t], acc);
    out[gph * HDIM + t] = acc;
}

extern "C" void kernel_launch(void* const* d_in, const int* in_sizes, int n_in,
                              void* d_out, int out_size, void* d_ws, size_t ws_size,
                              hipStream_t stream) {
    const float* x      = (const float*)d_in[0];
    const int*   ei     = (const int*)d_in[1];
    const float* ea     = (const float*)d_in[2];
    const int*   batch  = (const int*)d_in[3];
    const float* w_node = (const float*)d_in[4];
    const float* b_node = (const float*)d_in[5];
    const float* w_edge = (const float*)d_in[6];
    const float* b_edge = (const float*)d_in[7];
    const float* mp_w   = (const float*)d_in[8];
    const float* mp_b   = (const float*)d_in[9];
    const float* ln_g   = (const float*)d_in[10];
    const float* ln_b   = (const float*)d_in[11];
    const float* w_out  = (const float*)d_in[12];
    const float* b_out  = (const float*)d_in[13];
    float* out = (float*)d_out;
    int N = in_sizes[3];
    int E = in_sizes[2] / EDIM;
    float Ef = (float)E;
    int ntiles = (N + T0ROWS - 1) / T0ROWS;

    float* ws = (float*)d_ws;
    size_t off = 0;
    float* h        = ws + off; off += (size_t)N * HDIM;
    float* partials = ws + off; off += (size_t)1024 * 512;
    float* mean_msg = ws + off; off += 128;
    // ---- accumulator region (contiguous, zeroed every call) ----
    float* acc0     = ws + off;
    float* c_src    = ws + off; off += N + 64;
    float* c_dst    = ws + off; off += N + 64;
    float* sum_attr = ws + off; off += 8;
    float* xs       = ws + off; off += 136;
    float* sbuf1    = ws + off; off += 512;
    float* sbuf2    = ws + off; off += 512;
    float* pooled   = ws + off; off += NGRAPHS * HDIM;
    size_t zero_count = (size_t)(ws + off - acc0);
    hipMemsetAsync(acc0, 0, zero_count * sizeof(float), stream);

    k_hist<<<(E / 2 + 255) / 256, 256, 0, stream>>>(ei, c_src, c_dst, E);
    k_edgesum<<<128, 256, 0, stream>>>(ea, sum_attr, E);
    k_xsum<<<1024, 256, 0, stream>>>(x, c_src, c_dst, xs, N);

    const int NB0 = 768;
    const int NB = 1024;
    int cpb = (N + NB - 1) / NB;

    // layer 0
    k_mm<1><<<8, 256, 0, stream>>>(xs, sum_attr, w_edge, b_edge,
                                   mp_w, mp_b, mean_msg, Ef, w_node, b_node);
    k_upd0<<<NB0, 256, 0, stream>>>(x, w_node, b_node, mean_msg, ln_g, ln_b,
                                    c_src, c_dst, h, partials, N, ntiles);
    // layer 1
    k_red<<<(NB0 + 31) / 32, 256, 0, stream>>>(partials, sbuf1, NB0);
    k_mm<0><<<8, 256, 0, stream>>>(sbuf1, sum_attr, w_edge, b_edge,
                                   mp_w + (size_t)1 * 384 * HDIM,
                                   mp_b + (size_t)1 * HDIM, mean_msg, Ef,
                                   w_node, b_node);
    k_update<0><<<NB, 256, 0, stream>>>(h, mean_msg, ln_g, ln_b, c_src, c_dst,
                                        batch, partials, pooled, N, cpb);
    // layer 2
    k_red<<<NB / 32, 256, 0, stream>>>(partials, sbuf2, NB);
    k_mm<0><<<8, 256, 0, stream>>>(sbuf2, sum_attr, w_edge, b_edge,
                                   mp_w + (size_t)2 * 384 * HDIM,
                                   mp_b + (size_t)2 * HDIM, mean_msg, Ef,
                                   w_node, b_node);
    k_update<1><<<NB, 256, 0, stream>>>(h, mean_msg, ln_g, ln_b, c_src, c_dst,
                                        batch, partials, pooled, N, cpb);

    k_out<<<NGRAPHS, HDIM, 0, stream>>>(pooled, batch, w_out, b_out, out, N);
}

// Round 5
// 215.791 us; speedup vs baseline: 1.6358x; 1.1914x over previous
//
#include <hip/hip_runtime.h>

#define HDIM 128
#define XDIM 66
#define EDIM 6
#define NGRAPHS 256
#define LN_EPS 1e-5f
#define T0ROWS 64

#define HBINS 25600          // bins per range (100 KB LDS)
#define HR 4                 // index ranges: covers HR*HBINS = 102400 >= N
#define HB 32                // edge slices per (range, array)
#define CBINS (HR * HBINS)   // c_src / c_dst allocation size

// ---------------- K1a: partial LDS histograms ----------------
// blockIdx.x = (a*HR + r)*HB + s ; a: 0=src 1=dst, r: range, s: edge slice
__global__ __launch_bounds__(256) void k_hist_part(const int* __restrict__ ei,
        float* __restrict__ part, int E) {
    __shared__ float lh[HBINS];
    int b = blockIdx.x;
    int s = b & (HB - 1);
    int r = (b / HB) & (HR - 1);
    int a = b / (HB * HR);
    int t = threadIdx.x;
    for (int i = t; i < HBINS; i += 256) lh[i] = 0.f;
    __syncthreads();
    const int* src = ei + (size_t)a * E;
    int chunk = (((E + HB - 1) / HB) + 3) & ~3;
    int lo = s * chunk;
    int hi = min(E, lo + chunk);
    int base = r * HBINS;
    if ((E & 3) == 0) {
        for (int i = lo + t * 4; i < hi; i += 256 * 4) {
            if (i + 4 <= hi) {
                int4 v = *(const int4*)(src + i);
                unsigned u0 = (unsigned)(v.x - base);
                unsigned u1 = (unsigned)(v.y - base);
                unsigned u2 = (unsigned)(v.z - base);
                unsigned u3 = (unsigned)(v.w - base);
                if (u0 < HBINS) atomicAdd(&lh[u0], 1.0f);
                if (u1 < HBINS) atomicAdd(&lh[u1], 1.0f);
                if (u2 < HBINS) atomicAdd(&lh[u2], 1.0f);
                if (u3 < HBINS) atomicAdd(&lh[u3], 1.0f);
            } else {
                for (int j = i; j < hi; ++j) {
                    unsigned u = (unsigned)(src[j] - base);
                    if (u < HBINS) atomicAdd(&lh[u], 1.0f);
                }
            }
        }
    } else {
        for (int i = lo + t; i < hi; i += 256) {
            unsigned u = (unsigned)(src[i] - base);
            if (u < HBINS) atomicAdd(&lh[u], 1.0f);
        }
    }
    __syncthreads();
    float* dst = part + (size_t)b * HBINS;
    for (int i = t; i < HBINS / 4; i += 256)
        ((float4*)dst)[i] = ((const float4*)lh)[i];
}

// ---------------- K1b: reduce slices -> c_src, c_dst (fully written, incl. zero pad) ----------------
__global__ __launch_bounds__(256) void k_hist_red(const float* __restrict__ part,
        float* __restrict__ c_src, float* __restrict__ c_dst) {
    int n = blockIdx.x * 256 + threadIdx.x;   // 0 .. CBINS-1
    if (n >= CBINS) return;
    int r = n / HBINS, off = n - r * HBINS;
    const float* p0 = part + ((size_t)(0 * HR + r) * HB) * HBINS + off;
    const float* p1 = part + ((size_t)(1 * HR + r) * HB) * HBINS + off;
    float s0 = 0.f, s1 = 0.f;
#pragma unroll 8
    for (int s = 0; s < HB; ++s) {
        s0 += p0[(size_t)s * HBINS];
        s1 += p1[(size_t)s * HBINS];
    }
    c_src[n] = s0;
    c_dst[n] = s1;
}

// ---------------- K2: column-sum of edge_attr (E,6) ----------------
__global__ __launch_bounds__(256) void k_edgesum(const float* __restrict__ ea,
                                                 float* __restrict__ sum_attr, int E) {
    int nchunk = E >> 1;
    float a0 = 0, a1 = 0, a2 = 0, a3 = 0, a4 = 0, a5 = 0;
    for (int c = blockIdx.x * blockDim.x + threadIdx.x; c < nchunk;
         c += gridDim.x * blockDim.x) {
        const float4* p = (const float4*)(ea + (size_t)c * 12);
        float4 v0 = p[0], v1 = p[1], v2 = p[2];
        a0 += v0.x + v1.z;  a1 += v0.y + v1.w;  a2 += v0.z + v2.x;
        a3 += v0.w + v2.y;  a4 += v1.x + v2.z;  a5 += v1.y + v2.w;
    }
#pragma unroll
    for (int m = 32; m; m >>= 1) {
        a0 += __shfl_xor(a0, m); a1 += __shfl_xor(a1, m); a2 += __shfl_xor(a2, m);
        a3 += __shfl_xor(a3, m); a4 += __shfl_xor(a4, m); a5 += __shfl_xor(a5, m);
    }
    __shared__ float sbuf[4][6];
    int lane = threadIdx.x & 63, w = threadIdx.x >> 6;
    if (lane == 0) {
        sbuf[w][0] = a0; sbuf[w][1] = a1; sbuf[w][2] = a2;
        sbuf[w][3] = a3; sbuf[w][4] = a4; sbuf[w][5] = a5;
    }
    __syncthreads();
    if (threadIdx.x < 6) {
        float s = sbuf[0][threadIdx.x] + sbuf[1][threadIdx.x] +
                  sbuf[2][threadIdx.x] + sbuf[3][threadIdx.x];
        atomicAdd(&sum_attr[threadIdx.x], s);
    }
    if (blockIdx.x == 0 && threadIdx.x < 6 && (E & 1))
        atomicAdd(&sum_attr[threadIdx.x], ea[(size_t)(E - 1) * 6 + threadIdx.x]);
}

// ---------------- K3: weighted column sums of x (4-row ILP) ----------------
__global__ __launch_bounds__(256) void k_xsum(const float* __restrict__ x,
        const float* __restrict__ c_src, const float* __restrict__ c_dst,
        float* __restrict__ xs, int N) {
    int lane = threadIdx.x & 63, w = threadIdx.x >> 6;
    int wid = blockIdx.x * 4 + w, nw = gridDim.x * 4;
    float as0 = 0, ad0 = 0, as1 = 0, ad1 = 0;
    int Q = N >> 2;
    for (int q = wid; q < Q; q += nw) {
        int n = q * 4;
        const float* xr = x + (size_t)n * XDIM;
        float x0 = xr[lane];
        float x1 = xr[XDIM + lane];
        float x2 = xr[2 * XDIM + lane];
        float x3 = xr[3 * XDIM + lane];
        float4 cs = *(const float4*)(c_src + n);
        float4 cd = *(const float4*)(c_dst + n);
        as0 = fmaf(cs.x, x0, as0); as0 = fmaf(cs.y, x1, as0);
        as0 = fmaf(cs.z, x2, as0); as0 = fmaf(cs.w, x3, as0);
        ad0 = fmaf(cd.x, x0, ad0); ad0 = fmaf(cd.y, x1, ad0);
        ad0 = fmaf(cd.z, x2, ad0); ad0 = fmaf(cd.w, x3, ad0);
        if (lane < 2) {
            float e0 = xr[64 + lane];
            float e1 = xr[XDIM + 64 + lane];
            float e2 = xr[2 * XDIM + 64 + lane];
            float e3 = xr[3 * XDIM + 64 + lane];
            as1 = fmaf(cs.x, e0, as1); as1 = fmaf(cs.y, e1, as1);
            as1 = fmaf(cs.z, e2, as1); as1 = fmaf(cs.w, e3, as1);
            ad1 = fmaf(cd.x, e0, ad1); ad1 = fmaf(cd.y, e1, ad1);
            ad1 = fmaf(cd.z, e2, ad1); ad1 = fmaf(cd.w, e3, ad1);
        }
    }
    if (wid == 0) {
        for (int n = Q * 4; n < N; ++n) {
            const float* xr = x + (size_t)n * XDIM;
            float cs = c_src[n], cd = c_dst[n];
            float xv = xr[lane];
            as0 = fmaf(cs, xv, as0);
            ad0 = fmaf(cd, xv, ad0);
            if (lane < 2) {
                float xe = xr[64 + lane];
                as1 = fmaf(cs, xe, as1);
                ad1 = fmaf(cd, xe, ad1);
            }
        }
    }
    __shared__ float redS[4][XDIM], redD[4][XDIM];
    redS[w][lane] = as0;  redD[w][lane] = ad0;
    if (lane < 2) { redS[w][64 + lane] = as1;  redD[w][64 + lane] = ad1; }
    __syncthreads();
    int t = threadIdx.x;
    if (t < XDIM) {
        atomicAdd(&xs[t],        redS[0][t] + redS[1][t] + redS[2][t] + redS[3][t]);
        atomicAdd(&xs[XDIM + t], redD[0][t] + redD[1][t] + redD[2][t] + redD[3][t]);
    }
}

// ---------------- K6: mean_msg = ([s_src,s_dst,se] @ W)/E + mp_b ----------------
template <int FIRST>
__global__ __launch_bounds__(256) void k_mm(const float* __restrict__ sv,
        const float* __restrict__ sum_attr, const float* __restrict__ w_edge,
        const float* __restrict__ b_edge, const float* __restrict__ W,
        const float* __restrict__ mpb, float* __restrict__ mean_msg, float Ef,
        const float* __restrict__ w_node, const float* __restrict__ b_node) {
    __shared__ float sc[384];
    __shared__ float mred[256];
    int t = threadIdx.x;
    if (t < 128) {
        float ssrc, sdst;
        if (FIRST) {
            ssrc = Ef * b_node[t];
            sdst = ssrc;
#pragma unroll
            for (int k = 0; k < XDIM; ++k) {
                float wv = w_node[k * HDIM + t];
                ssrc = fmaf(sv[k], wv, ssrc);
                sdst = fmaf(sv[XDIM + k], wv, sdst);
            }
        } else {
            ssrc = sv[t] + sv[t + 128];
            sdst = sv[256 + t] + sv[384 + t];
        }
        sc[t] = ssrc;
        sc[128 + t] = sdst;
        float se = Ef * b_edge[t];
#pragma unroll
        for (int k = 0; k < EDIM; ++k) se = fmaf(sum_attr[k], w_edge[k * HDIM + t], se);
        sc[256 + t] = se;
    }
    __syncthreads();
    int col = blockIdx.x * 16 + (t & 15);
    int rg = t >> 4;
    float acc = 0.f;
#pragma unroll 4
    for (int r = rg * 24; r < rg * 24 + 24; ++r)
        acc = fmaf(sc[r], W[r * HDIM + col], acc);
    mred[t] = acc;
    __syncthreads();
    if (t < 16) {
        float s = 0.f;
#pragma unroll
        for (int g = 0; g < 16; ++g) s += mred[g * 16 + t];
        mean_msg[blockIdx.x * 16 + t] = s / Ef + mpb[blockIdx.x * 16 + t];
    }
}

// ---------------- K5: reduce per-block partials -> sbuf[512] ----------------
__global__ __launch_bounds__(256) void k_red(const float* __restrict__ partials,
                                             float* __restrict__ sbuf, int nb) {
    int b0 = blockIdx.x * 32;
    int b1 = min(nb, b0 + 32);
    int t = threadIdx.x;
    float s0 = 0.f, s1 = 0.f;
    for (int b = b0; b < b1; ++b) {
        const float* row = partials + (size_t)b * 512;
        s0 += row[t];
        s1 += row[t + 256];
    }
    atomicAdd(&sbuf[t], s0);
    atomicAdd(&sbuf[t + 256], s1);
}

// ---------------- K7: fused layer-0: tiled LDS GEMM + LN + relu + weighted sums ----------------
__global__ __launch_bounds__(256) void k_upd0(
        const float* __restrict__ x, const float* __restrict__ w_node,
        const float* __restrict__ b_node, const float* __restrict__ mean_msg,
        const float* __restrict__ ln_g, const float* __restrict__ ln_b,
        const float* __restrict__ c_src, const float* __restrict__ c_dst,
        float* __restrict__ h, float* __restrict__ partials, int N, int ntiles) {
    __shared__ float wl[XDIM * HDIM];
    __shared__ float xl[T0ROWS * XDIM];
    int t = threadIdx.x;
    int cg = t & 31, rg = t >> 5;
    int c0 = cg * 4;
    for (int i = t; i < XDIM * HDIM / 2; i += 256)
        ((float2*)wl)[i] = ((const float2*)w_node)[i];
    float4 b4 = *(const float4*)(b_node + c0);
    float4 m4 = *(const float4*)(mean_msg + c0);
    float4 bm = {b4.x + m4.x, b4.y + m4.y, b4.z + m4.z, b4.w + m4.w};
    float4 g4  = *(const float4*)(ln_g + c0);
    float4 lb4 = *(const float4*)(ln_b + c0);
    float4 accS = {0, 0, 0, 0}, accD = {0, 0, 0, 0};

    for (int tile = blockIdx.x; tile < ntiles; tile += gridDim.x) {
        int rowbase = tile * T0ROWS;
        const float* xg = x + (size_t)rowbase * XDIM;
        int vr = min(T0ROWS, N - rowbase);
        int lim = vr * XDIM;
        __syncthreads();
        for (int i = t; i < T0ROWS * XDIM / 2; i += 256) {
            int e = i * 2;
            float2 vv;
            if (e + 2 <= lim) vv = *(const float2*)(xg + e);
            else { vv.x = (e < lim) ? xg[e] : 0.f; vv.y = (e + 1 < lim) ? xg[e + 1] : 0.f; }
            ((float2*)xl)[i] = vv;
        }
        __syncthreads();

        float4 acc[8];
#pragma unroll
        for (int j = 0; j < 8; ++j) acc[j] = bm;
        const float* xrow = xl + rg * 8 * XDIM;
#pragma unroll 6
        for (int k = 0; k < XDIM; ++k) {
            float4 wv = *(const float4*)(wl + k * HDIM + c0);
#pragma unroll
            for (int j = 0; j < 8; ++j) {
                float xv = xrow[j * XDIM + k];
                acc[j].x = fmaf(xv, wv.x, acc[j].x);
                acc[j].y = fmaf(xv, wv.y, acc[j].y);
                acc[j].z = fmaf(xv, wv.z, acc[j].z);
                acc[j].w = fmaf(xv, wv.w, acc[j].w);
            }
        }
        float4 csA = *(const float4*)(c_src + rowbase + rg * 8);
        float4 csB = *(const float4*)(c_src + rowbase + rg * 8 + 4);
        float4 cdA = *(const float4*)(c_dst + rowbase + rg * 8);
        float4 cdB = *(const float4*)(c_dst + rowbase + rg * 8 + 4);
        float csArr[8] = {csA.x, csA.y, csA.z, csA.w, csB.x, csB.y, csB.z, csB.w};
        float cdArr[8] = {cdA.x, cdA.y, cdA.z, cdA.w, cdB.x, cdB.y, cdB.z, cdB.w};
#pragma unroll
        for (int j = 0; j < 8; ++j) {
            float4 a = acc[j];
            float s = a.x + a.y + a.z + a.w;
#pragma unroll
            for (int m = 16; m; m >>= 1) s += __shfl_xor(s, m);
            float mu = s * (1.0f / HDIM);
            float d0 = a.x - mu, d1 = a.y - mu, d2 = a.z - mu, d3 = a.w - mu;
            float q = d0 * d0 + d1 * d1 + d2 * d2 + d3 * d3;
#pragma unroll
            for (int m = 16; m; m >>= 1) q += __shfl_xor(q, m);
            float rs = rsqrtf(q * (1.0f / HDIM) + LN_EPS);
            float4 o;
            o.x = fmaxf(0.f, fmaf(d0 * rs, g4.x, lb4.x));
            o.y = fmaxf(0.f, fmaf(d1 * rs, g4.y, lb4.y));
            o.z = fmaxf(0.f, fmaf(d2 * rs, g4.z, lb4.z));
            o.w = fmaxf(0.f, fmaf(d3 * rs, g4.w, lb4.w));
            int row = rowbase + rg * 8 + j;
            if (row < N)
                *(float4*)(h + (size_t)row * HDIM + c0) = o;
            float cs = csArr[j], cd = cdArr[j];
            accS.x = fmaf(cs, o.x, accS.x); accS.y = fmaf(cs, o.y, accS.y);
            accS.z = fmaf(cs, o.z, accS.z); accS.w = fmaf(cs, o.w, accS.w);
            accD.x = fmaf(cd, o.x, accD.x); accD.y = fmaf(cd, o.y, accD.y);
            accD.z = fmaf(cd, o.z, accD.z); accD.w = fmaf(cd, o.w, accD.w);
        }
    }
    __syncthreads();
    float* red = xl;
    *(float4*)(red + rg * HDIM + c0) = accS;
    *(float4*)(red + 1024 + rg * HDIM + c0) = accD;
    __syncthreads();
    if (t < 128) {
        float s = 0.f, d = 0.f;
#pragma unroll
        for (int gi = 0; gi < 8; ++gi) {
            s += red[gi * HDIM + t];
            d += red[1024 + gi * HDIM + t];
        }
        float* row = partials + (size_t)blockIdx.x * 512;
        row[t] = s;        row[t + 128] = 0.f;
        row[t + 256] = d;  row[t + 384] = 0.f;
    }
}

// ---------------- LN helper ----------------
__device__ __forceinline__ float2 ln_relu2(float2 v, float2 g, float2 bb) {
    float s = v.x + v.y;
#pragma unroll
    for (int m = 32; m; m >>= 1) s += __shfl_xor(s, m);
    float mu = s * (1.0f / HDIM);
    float dx = v.x - mu, dy = v.y - mu;
    float q = dx * dx + dy * dy;
#pragma unroll
    for (int m = 32; m; m >>= 1) q += __shfl_xor(q, m);
    float rs = rsqrtf(q * (1.0f / HDIM) + LN_EPS);
    float2 o;
    o.x = fmaxf(0.f, fmaf(dx * rs, g.x, bb.x));
    o.y = fmaxf(0.f, fmaf(dy * rs, g.y, bb.y));
    return o;
}

// ---------------- K8: h = relu(LN(h + mm)); next-layer sums or pooling ----------------
template <int LAST>
__global__ __launch_bounds__(256) void k_update(
        float* __restrict__ h, const float* __restrict__ mean_msg,
        const float* __restrict__ ln_g, const float* __restrict__ ln_b,
        const float* __restrict__ c_src, const float* __restrict__ c_dst,
        const int* __restrict__ batch, float* __restrict__ partials,
        float* __restrict__ pooled, int N, int cpb) {
    int t = threadIdx.x;
    int lane = t & 63, w = t >> 6;
    int c0 = lane * 2;
    float2 mm = *(const float2*)(mean_msg + c0);
    float2 g  = *(const float2*)(ln_g + c0);
    float2 bb = *(const float2*)(ln_b + c0);
    int start = blockIdx.x * cpb;
    int end = min(N, start + cpb);
    int spw = (cpb + 3) >> 2;
    int ns = start + w * spw;
    int ne = min(end, ns + spw);
    float2 accS = {0.f, 0.f}, accD = {0.f, 0.f}, accP = {0.f, 0.f};
    int cur_g = -1;
    int n = ns;
    for (; n + 4 <= ne; n += 4) {
        float2 v0 = *(const float2*)(h + (size_t)(n    ) * HDIM + c0);
        float2 v1 = *(const float2*)(h + (size_t)(n + 1) * HDIM + c0);
        float2 v2 = *(const float2*)(h + (size_t)(n + 2) * HDIM + c0);
        float2 v3 = *(const float2*)(h + (size_t)(n + 3) * HDIM + c0);
        v0.x += mm.x; v0.y += mm.y;  v1.x += mm.x; v1.y += mm.y;
        v2.x += mm.x; v2.y += mm.y;  v3.x += mm.x; v3.y += mm.y;
        float2 o0 = ln_relu2(v0, g, bb);
        float2 o1 = ln_relu2(v1, g, bb);
        float2 o2 = ln_relu2(v2, g, bb);
        float2 o3 = ln_relu2(v3, g, bb);
        if (LAST) {
            int gi[4] = {batch[n], batch[n + 1], batch[n + 2], batch[n + 3]};
            float2 oo[4] = {o0, o1, o2, o3};
#pragma unroll
            for (int r = 0; r < 4; ++r) {
                if (gi[r] != cur_g) {
                    if (cur_g >= 0) {
                        atomicAdd(&pooled[cur_g * HDIM + c0],     accP.x);
                        atomicAdd(&pooled[cur_g * HDIM + c0 + 1], accP.y);
                    }
                    accP.x = 0.f; accP.y = 0.f;
                    cur_g = gi[r];
                }
                accP.x += oo[r].x; accP.y += oo[r].y;
            }
        } else {
            *(float2*)(h + (size_t)(n    ) * HDIM + c0) = o0;
            *(float2*)(h + (size_t)(n + 1) * HDIM + c0) = o1;
            *(float2*)(h + (size_t)(n + 2) * HDIM + c0) = o2;
            *(float2*)(h + (size_t)(n + 3) * HDIM + c0) = o3;
            float cs0 = c_src[n], cs1 = c_src[n+1], cs2 = c_src[n+2], cs3 = c_src[n+3];
            float cd0 = c_dst[n], cd1 = c_dst[n+1], cd2 = c_dst[n+2], cd3 = c_dst[n+3];
            accS.x = fmaf(cs0, o0.x, accS.x); accS.y = fmaf(cs0, o0.y, accS.y);
            accS.x = fmaf(cs1, o1.x, accS.x); accS.y = fmaf(cs1, o1.y, accS.y);
            accS.x = fmaf(cs2, o2.x, accS.x); accS.y = fmaf(cs2, o2.y, accS.y);
            accS.x = fmaf(cs3, o3.x, accS.x); accS.y = fmaf(cs3, o3.y, accS.y);
            accD.x = fmaf(cd0, o0.x, accD.x); accD.y = fmaf(cd0, o0.y, accD.y);
            accD.x = fmaf(cd1, o1.x, accD.x); accD.y = fmaf(cd1, o1.y, accD.y);
            accD.x = fmaf(cd2, o2.x, accD.x); accD.y = fmaf(cd2, o2.y, accD.y);
            accD.x = fmaf(cd3, o3.x, accD.x); accD.y = fmaf(cd3, o3.y, accD.y);
        }
    }
    for (; n < ne; ++n) {
        float2 v = *(const float2*)(h + (size_t)n * HDIM + c0);
        v.x += mm.x; v.y += mm.y;
        float2 o = ln_relu2(v, g, bb);
        if (LAST) {
            int gg = batch[n];
            if (gg != cur_g) {
                if (cur_g >= 0) {
                    atomicAdd(&pooled[cur_g * HDIM + c0],     accP.x);
                    atomicAdd(&pooled[cur_g * HDIM + c0 + 1], accP.y);
                }
                accP.x = 0.f; accP.y = 0.f;
                cur_g = gg;
            }
            accP.x += o.x; accP.y += o.y;
        } else {
            *(float2*)(h + (size_t)n * HDIM + c0) = o;
            float cs = c_src[n], cd = c_dst[n];
            accS.x = fmaf(cs, o.x, accS.x); accS.y = fmaf(cs, o.y, accS.y);
            accD.x = fmaf(cd, o.x, accD.x); accD.y = fmaf(cd, o.y, accD.y);
        }
    }
    if (LAST) {
        if (cur_g >= 0) {
            atomicAdd(&pooled[cur_g * HDIM + c0],     accP.x);
            atomicAdd(&pooled[cur_g * HDIM + c0 + 1], accP.y);
        }
    } else {
        __shared__ float sb[HDIM], db[HDIM];
        if (t < HDIM) { sb[t] = 0.f; db[t] = 0.f; }
        __syncthreads();
        atomicAdd(&sb[c0], accS.x); atomicAdd(&sb[c0 + 1], accS.y);
        atomicAdd(&db[c0], accD.x); atomicAdd(&db[c0 + 1], accD.y);
        __syncthreads();
        float* row = partials + (size_t)blockIdx.x * 512;
        if (t < 128) {
            row[t] = sb[t];        row[t + 128] = 0.f;
            row[t + 256] = db[t];  row[t + 384] = 0.f;
        }
    }
}

// ---------------- K9: out = (pooled / max(cnt,1)) @ w_out + b_out ----------------
__global__ __launch_bounds__(128) void k_out(const float* __restrict__ pooled,
        const int* __restrict__ batch, const float* __restrict__ w_out,
        const float* __restrict__ b_out, float* __restrict__ out, int N) {
    int gph = blockIdx.x;
    int t = threadIdx.x;
    __shared__ float p[HDIM];
    __shared__ int cntS;
    if (t == 0) {
        int lo = 0, hi = N;
        while (lo < hi) { int mid = (lo + hi) >> 1; if (batch[mid] < gph) lo = mid + 1; else hi = mid; }
        int lo2 = lo, hi2 = N;
        while (lo2 < hi2) { int mid = (lo2 + hi2) >> 1; if (batch[mid] <= gph) lo2 = mid + 1; else hi2 = mid; }
        cntS = lo2 - lo;
    }
    __syncthreads();
    float inv = 1.0f / fmaxf((float)cntS, 1.0f);
    p[t] = pooled[gph * HDIM + t] * inv;
    __syncthreads();
    float acc = b_out[t];
#pragma unroll 8
    for (int k = 0; k < HDIM; ++k) acc = fmaf(p[k], w_out[k * HDIM + t], acc);
    out[gph * HDIM + t] = acc;
}

extern "C" void kernel_launch(void* const* d_in, const int* in_sizes, int n_in,
                              void* d_out, int out_size, void* d_ws, size_t ws_size,
                              hipStream_t stream) {
    const float* x      = (const float*)d_in[0];
    const int*   ei     = (const int*)d_in[1];
    const float* ea     = (const float*)d_in[2];
    const int*   batch  = (const int*)d_in[3];
    const float* w_node = (const float*)d_in[4];
    const float* b_node = (const float*)d_in[5];
    const float* w_edge = (const float*)d_in[6];
    const float* b_edge = (const float*)d_in[7];
    const float* mp_w   = (const float*)d_in[8];
    const float* mp_b   = (const float*)d_in[9];
    const float* ln_g   = (const float*)d_in[10];
    const float* ln_b   = (const float*)d_in[11];
    const float* w_out  = (const float*)d_in[12];
    const float* b_out  = (const float*)d_in[13];
    float* out = (float*)d_out;
    int N = in_sizes[3];
    int E = in_sizes[2] / EDIM;
    float Ef = (float)E;
    int ntiles = (N + T0ROWS - 1) / T0ROWS;

    float* ws = (float*)d_ws;
    size_t off = 0;
    float* h        = ws + off; off += (size_t)N * HDIM;       // hist partials overlay here
    float* hist_part = h;   // 2*HR*HB*HBINS = 26.2MB <= N*HDIM*4B = 51.2MB
    float* partials = ws + off; off += (size_t)1024 * 512;
    float* mean_msg = ws + off; off += 128;
    float* c_src    = ws + off; off += CBINS;   // fully written by k_hist_red
    float* c_dst    = ws + off; off += CBINS;
    // ---- accumulator region (contiguous, zeroed every call) ----
    float* acc0     = ws + off;
    float* sum_attr = ws + off; off += 8;
    float* xs       = ws + off; off += 136;
    float* sbuf1    = ws + off; off += 512;
    float* sbuf2    = ws + off; off += 512;
    float* pooled   = ws + off; off += NGRAPHS * HDIM;
    size_t zero_count = (size_t)(ws + off - acc0);
    hipMemsetAsync(acc0, 0, zero_count * sizeof(float), stream);

    k_hist_part<<<2 * HR * HB, 256, 0, stream>>>(ei, hist_part, E);
    k_hist_red<<<(CBINS + 255) / 256, 256, 0, stream>>>(hist_part, c_src, c_dst);
    k_edgesum<<<128, 256, 0, stream>>>(ea, sum_attr, E);
    k_xsum<<<1024, 256, 0, stream>>>(x, c_src, c_dst, xs, N);

    const int NB0 = 768;
    const int NB = 1024;
    int cpb = (N + NB - 1) / NB;

    // layer 0
    k_mm<1><<<8, 256, 0, stream>>>(xs, sum_attr, w_edge, b_edge,
                                   mp_w, mp_b, mean_msg, Ef, w_node, b_node);
    k_upd0<<<NB0, 256, 0, stream>>>(x, w_node, b_node, mean_msg, ln_g, ln_b,
                                    c_src, c_dst, h, partials, N, ntiles);
    // layer 1
    k_red<<<(NB0 + 31) / 32, 256, 0, stream>>>(partials, sbuf1, NB0);
    k_mm<0><<<8, 256, 0, stream>>>(sbuf1, sum_attr, w_edge, b_edge,
                                   mp_w + (size_t)1 * 384 * HDIM,
                                   mp_b + (size_t)1 * HDIM, mean_msg, Ef,
                                   w_node, b_node);
    k_update<0><<<NB, 256, 0, stream>>>(h, mean_msg, ln_g, ln_b, c_src, c_dst,
                                        batch, partials, pooled, N, cpb);
    // layer 2
    k_red<<<NB / 32, 256, 0, stream>>>(partials, sbuf2, NB);
    k_mm<0><<<8, 256, 0, stream>>>(sbuf2, sum_attr, w_edge, b_edge,
                                   mp_w + (size_t)2 * 384 * HDIM,
                                   mp_b + (size_t)2 * HDIM, mean_msg, Ef,
                                   w_node, b_node);
    k_update<1><<<NB, 256, 0, stream>>>(h, mean_msg, ln_g, ln_b, c_src, c_dst,
                                        batch, partials, pooled, N, cpb);

    k_out<<<NGRAPHS, HDIM, 0, stream>>>(pooled, batch, w_out, b_out, out, N);
}

// Round 6
// 178.678 us; speedup vs baseline: 1.9756x; 1.2077x over previous
//
#include <hip/hip_runtime.h>

#define HDIM 128
#define XDIM 66
#define EDIM 6
#define NGRAPHS 256
#define LN_EPS 1e-5f
#define T0ROWS 64

#define HBINS 25600          // bins per range (100 KB LDS)
#define HR 4                 // index ranges: covers HR*HBINS = 102400 >= N
#define HB 32                // edge slices per (range, array)
#define CBINS (HR * HBINS)   // c_src / c_dst allocation size
#define NBX 1024             // k_xsum grid

// ---------------- K1a: partial LDS histograms ----------------
__global__ __launch_bounds__(256) void k_hist_part(const int* __restrict__ ei,
        float* __restrict__ part, int E) {
    __shared__ float lh[HBINS];
    int b = blockIdx.x;
    int s = b & (HB - 1);
    int r = (b / HB) & (HR - 1);
    int a = b / (HB * HR);
    int t = threadIdx.x;
    for (int i = t; i < HBINS; i += 256) lh[i] = 0.f;
    __syncthreads();
    const int* src = ei + (size_t)a * E;
    int chunk = (((E + HB - 1) / HB) + 3) & ~3;
    int lo = s * chunk;
    int hi = min(E, lo + chunk);
    int base = r * HBINS;
    if ((E & 3) == 0) {
        for (int i = lo + t * 4; i < hi; i += 256 * 4) {
            if (i + 4 <= hi) {
                int4 v = *(const int4*)(src + i);
                unsigned u0 = (unsigned)(v.x - base);
                unsigned u1 = (unsigned)(v.y - base);
                unsigned u2 = (unsigned)(v.z - base);
                unsigned u3 = (unsigned)(v.w - base);
                if (u0 < HBINS) atomicAdd(&lh[u0], 1.0f);
                if (u1 < HBINS) atomicAdd(&lh[u1], 1.0f);
                if (u2 < HBINS) atomicAdd(&lh[u2], 1.0f);
                if (u3 < HBINS) atomicAdd(&lh[u3], 1.0f);
            } else {
                for (int j = i; j < hi; ++j) {
                    unsigned u = (unsigned)(src[j] - base);
                    if (u < HBINS) atomicAdd(&lh[u], 1.0f);
                }
            }
        }
    } else {
        for (int i = lo + t; i < hi; i += 256) {
            unsigned u = (unsigned)(src[i] - base);
            if (u < HBINS) atomicAdd(&lh[u], 1.0f);
        }
    }
    __syncthreads();
    float* dst = part + (size_t)b * HBINS;
    for (int i = t; i < HBINS / 4; i += 256)
        ((float4*)dst)[i] = ((const float4*)lh)[i];
}

// ---------------- K1b: reduce slices -> c_src, c_dst ----------------
__global__ __launch_bounds__(256) void k_hist_red(const float* __restrict__ part,
        float* __restrict__ c_src, float* __restrict__ c_dst) {
    int n = blockIdx.x * 256 + threadIdx.x;
    if (n >= CBINS) return;
    int r = n / HBINS, off = n - r * HBINS;
    const float* p0 = part + ((size_t)(0 * HR + r) * HB) * HBINS + off;
    const float* p1 = part + ((size_t)(1 * HR + r) * HB) * HBINS + off;
    float s0 = 0.f, s1 = 0.f;
#pragma unroll 8
    for (int s = 0; s < HB; ++s) {
        s0 += p0[(size_t)s * HBINS];
        s1 += p1[(size_t)s * HBINS];
    }
    c_src[n] = s0;
    c_dst[n] = s1;
}

// ---------------- K2: column-sum of edge_attr (E,6) ----------------
__global__ __launch_bounds__(256) void k_edgesum(const float* __restrict__ ea,
                                                 float* __restrict__ sum_attr, int E) {
    int nchunk = E >> 1;
    float a0 = 0, a1 = 0, a2 = 0, a3 = 0, a4 = 0, a5 = 0;
    for (int c = blockIdx.x * blockDim.x + threadIdx.x; c < nchunk;
         c += gridDim.x * blockDim.x) {
        const float4* p = (const float4*)(ea + (size_t)c * 12);
        float4 v0 = p[0], v1 = p[1], v2 = p[2];
        a0 += v0.x + v1.z;  a1 += v0.y + v1.w;  a2 += v0.z + v2.x;
        a3 += v0.w + v2.y;  a4 += v1.x + v2.z;  a5 += v1.y + v2.w;
    }
#pragma unroll
    for (int m = 32; m; m >>= 1) {
        a0 += __shfl_xor(a0, m); a1 += __shfl_xor(a1, m); a2 += __shfl_xor(a2, m);
        a3 += __shfl_xor(a3, m); a4 += __shfl_xor(a4, m); a5 += __shfl_xor(a5, m);
    }
    __shared__ float sbuf[4][6];
    int lane = threadIdx.x & 63, w = threadIdx.x >> 6;
    if (lane == 0) {
        sbuf[w][0] = a0; sbuf[w][1] = a1; sbuf[w][2] = a2;
        sbuf[w][3] = a3; sbuf[w][4] = a4; sbuf[w][5] = a5;
    }
    __syncthreads();
    if (threadIdx.x < 6) {
        float s = sbuf[0][threadIdx.x] + sbuf[1][threadIdx.x] +
                  sbuf[2][threadIdx.x] + sbuf[3][threadIdx.x];
        atomicAdd(&sum_attr[threadIdx.x], s);
    }
    if (blockIdx.x == 0 && threadIdx.x < 6 && (E & 1))
        atomicAdd(&sum_attr[threadIdx.x], ea[(size_t)(E - 1) * 6 + threadIdx.x]);
}

// ---------------- K3: weighted column sums of x -> per-block partials (NO atomics) ----------------
__global__ __launch_bounds__(256) void k_xsum(const float* __restrict__ x,
        const float* __restrict__ c_src, const float* __restrict__ c_dst,
        float* __restrict__ xpart, int N) {
    int lane = threadIdx.x & 63, w = threadIdx.x >> 6;
    int wid = blockIdx.x * 4 + w, nw = gridDim.x * 4;
    float as0 = 0, ad0 = 0, as1 = 0, ad1 = 0;
    int Q = N >> 2;
    for (int q = wid; q < Q; q += nw) {
        int n = q * 4;
        const float* xr = x + (size_t)n * XDIM;
        float x0 = xr[lane];
        float x1 = xr[XDIM + lane];
        float x2 = xr[2 * XDIM + lane];
        float x3 = xr[3 * XDIM + lane];
        float4 cs = *(const float4*)(c_src + n);
        float4 cd = *(const float4*)(c_dst + n);
        as0 = fmaf(cs.x, x0, as0); as0 = fmaf(cs.y, x1, as0);
        as0 = fmaf(cs.z, x2, as0); as0 = fmaf(cs.w, x3, as0);
        ad0 = fmaf(cd.x, x0, ad0); ad0 = fmaf(cd.y, x1, ad0);
        ad0 = fmaf(cd.z, x2, ad0); ad0 = fmaf(cd.w, x3, ad0);
        if (lane < 2) {
            float e0 = xr[64 + lane];
            float e1 = xr[XDIM + 64 + lane];
            float e2 = xr[2 * XDIM + 64 + lane];
            float e3 = xr[3 * XDIM + 64 + lane];
            as1 = fmaf(cs.x, e0, as1); as1 = fmaf(cs.y, e1, as1);
            as1 = fmaf(cs.z, e2, as1); as1 = fmaf(cs.w, e3, as1);
            ad1 = fmaf(cd.x, e0, ad1); ad1 = fmaf(cd.y, e1, ad1);
            ad1 = fmaf(cd.z, e2, ad1); ad1 = fmaf(cd.w, e3, ad1);
        }
    }
    if (wid == 0) {
        for (int n = Q * 4; n < N; ++n) {
            const float* xr = x + (size_t)n * XDIM;
            float cs = c_src[n], cd = c_dst[n];
            float xv = xr[lane];
            as0 = fmaf(cs, xv, as0);
            ad0 = fmaf(cd, xv, ad0);
            if (lane < 2) {
                float xe = xr[64 + lane];
                as1 = fmaf(cs, xe, as1);
                ad1 = fmaf(cd, xe, ad1);
            }
        }
    }
    __shared__ float redS[4][XDIM], redD[4][XDIM];
    redS[w][lane] = as0;  redD[w][lane] = ad0;
    if (lane < 2) { redS[w][64 + lane] = as1;  redD[w][64 + lane] = ad1; }
    __syncthreads();
    int t = threadIdx.x;
    float* xp = xpart + (size_t)blockIdx.x * 136;
    if (t < XDIM) {
        xp[t]        = redS[0][t] + redS[1][t] + redS[2][t] + redS[3][t];
        xp[XDIM + t] = redD[0][t] + redD[1][t] + redD[2][t] + redD[3][t];
    }
}

// ---------------- K3b: reduce xpart rows -> xs[132] ----------------
__global__ __launch_bounds__(64) void k_xred(const float* __restrict__ xpart,
                                             float* __restrict__ xs, int nb) {
    int e = blockIdx.x;          // 0 .. 131
    int lane = threadIdx.x;
    float s = 0.f;
    for (int b = lane; b < nb; b += 64)
        s += xpart[(size_t)b * 136 + e];
#pragma unroll
    for (int m = 32; m; m >>= 1) s += __shfl_xor(s, m);
    if (lane == 0) xs[e] = s;
}

// ---------------- K6: mean_msg = ([s_src,s_dst,se] @ W)/E + mp_b ----------------
template <int FIRST>
__global__ __launch_bounds__(256) void k_mm(const float* __restrict__ sv,
        const float* __restrict__ sum_attr, const float* __restrict__ w_edge,
        const float* __restrict__ b_edge, const float* __restrict__ W,
        const float* __restrict__ mpb, float* __restrict__ mean_msg, float Ef,
        const float* __restrict__ w_node, const float* __restrict__ b_node) {
    __shared__ float sc[384];
    __shared__ float mred[256];
    int t = threadIdx.x;
    if (t < 128) {
        float ssrc, sdst;
        if (FIRST) {
            ssrc = Ef * b_node[t];
            sdst = ssrc;
#pragma unroll
            for (int k = 0; k < XDIM; ++k) {
                float wv = w_node[k * HDIM + t];
                ssrc = fmaf(sv[k], wv, ssrc);
                sdst = fmaf(sv[XDIM + k], wv, sdst);
            }
        } else {
            ssrc = sv[t] + sv[t + 128];
            sdst = sv[256 + t] + sv[384 + t];
        }
        sc[t] = ssrc;
        sc[128 + t] = sdst;
        float se = Ef * b_edge[t];
#pragma unroll
        for (int k = 0; k < EDIM; ++k) se = fmaf(sum_attr[k], w_edge[k * HDIM + t], se);
        sc[256 + t] = se;
    }
    __syncthreads();
    int col = blockIdx.x * 16 + (t & 15);
    int rg = t >> 4;
    float acc = 0.f;
#pragma unroll 4
    for (int r = rg * 24; r < rg * 24 + 24; ++r)
        acc = fmaf(sc[r], W[r * HDIM + col], acc);
    mred[t] = acc;
    __syncthreads();
    if (t < 16) {
        float s = 0.f;
#pragma unroll
        for (int g = 0; g < 16; ++g) s += mred[g * 16 + t];
        mean_msg[blockIdx.x * 16 + t] = s / Ef + mpb[blockIdx.x * 16 + t];
    }
}

// ---------------- K5: reduce per-block partials -> sbuf[512] ----------------
__global__ __launch_bounds__(256) void k_red(const float* __restrict__ partials,
                                             float* __restrict__ sbuf, int nb) {
    int b0 = blockIdx.x * 32;
    int b1 = min(nb, b0 + 32);
    int t = threadIdx.x;
    float s0 = 0.f, s1 = 0.f;
    for (int b = b0; b < b1; ++b) {
        const float* row = partials + (size_t)b * 512;
        s0 += row[t];
        s1 += row[t + 256];
    }
    atomicAdd(&sbuf[t], s0);
    atomicAdd(&sbuf[t + 256], s1);
}

// ---------------- K7: fused layer-0: tiled LDS GEMM + LN + relu + weighted sums ----------------
__global__ __launch_bounds__(256) void k_upd0(
        const float* __restrict__ x, const float* __restrict__ w_node,
        const float* __restrict__ b_node, const float* __restrict__ mean_msg,
        const float* __restrict__ ln_g, const float* __restrict__ ln_b,
        const float* __restrict__ c_src, const float* __restrict__ c_dst,
        float* __restrict__ h, float* __restrict__ partials, int N, int ntiles) {
    __shared__ float wl[XDIM * HDIM];
    __shared__ float xl[T0ROWS * XDIM];
    int t = threadIdx.x;
    int cg = t & 31, rg = t >> 5;
    int c0 = cg * 4;
    for (int i = t; i < XDIM * HDIM / 2; i += 256)
        ((float2*)wl)[i] = ((const float2*)w_node)[i];
    float4 b4 = *(const float4*)(b_node + c0);
    float4 m4 = *(const float4*)(mean_msg + c0);
    float4 bm = {b4.x + m4.x, b4.y + m4.y, b4.z + m4.z, b4.w + m4.w};
    float4 g4  = *(const float4*)(ln_g + c0);
    float4 lb4 = *(const float4*)(ln_b + c0);
    float4 accS = {0, 0, 0, 0}, accD = {0, 0, 0, 0};

    for (int tile = blockIdx.x; tile < ntiles; tile += gridDim.x) {
        int rowbase = tile * T0ROWS;
        const float* xg = x + (size_t)rowbase * XDIM;
        int vr = min(T0ROWS, N - rowbase);
        int lim = vr * XDIM;
        __syncthreads();
        for (int i = t; i < T0ROWS * XDIM / 2; i += 256) {
            int e = i * 2;
            float2 vv;
            if (e + 2 <= lim) vv = *(const float2*)(xg + e);
            else { vv.x = (e < lim) ? xg[e] : 0.f; vv.y = (e + 1 < lim) ? xg[e + 1] : 0.f; }
            ((float2*)xl)[i] = vv;
        }
        __syncthreads();

        float4 acc[8];
#pragma unroll
        for (int j = 0; j < 8; ++j) acc[j] = bm;
        const float* xrow = xl + rg * 8 * XDIM;
#pragma unroll 6
        for (int k = 0; k < XDIM; ++k) {
            float4 wv = *(const float4*)(wl + k * HDIM + c0);
#pragma unroll
            for (int j = 0; j < 8; ++j) {
                float xv = xrow[j * XDIM + k];
                acc[j].x = fmaf(xv, wv.x, acc[j].x);
                acc[j].y = fmaf(xv, wv.y, acc[j].y);
                acc[j].z = fmaf(xv, wv.z, acc[j].z);
                acc[j].w = fmaf(xv, wv.w, acc[j].w);
            }
        }
        float4 csA = *(const float4*)(c_src + rowbase + rg * 8);
        float4 csB = *(const float4*)(c_src + rowbase + rg * 8 + 4);
        float4 cdA = *(const float4*)(c_dst + rowbase + rg * 8);
        float4 cdB = *(const float4*)(c_dst + rowbase + rg * 8 + 4);
        float csArr[8] = {csA.x, csA.y, csA.z, csA.w, csB.x, csB.y, csB.z, csB.w};
        float cdArr[8] = {cdA.x, cdA.y, cdA.z, cdA.w, cdB.x, cdB.y, cdB.z, cdB.w};
#pragma unroll
        for (int j = 0; j < 8; ++j) {
            float4 a = acc[j];
            float s = a.x + a.y + a.z + a.w;
#pragma unroll
            for (int m = 16; m; m >>= 1) s += __shfl_xor(s, m);
            float mu = s * (1.0f / HDIM);
            float d0 = a.x - mu, d1 = a.y - mu, d2 = a.z - mu, d3 = a.w - mu;
            float q = d0 * d0 + d1 * d1 + d2 * d2 + d3 * d3;
#pragma unroll
            for (int m = 16; m; m >>= 1) q += __shfl_xor(q, m);
            float rs = rsqrtf(q * (1.0f / HDIM) + LN_EPS);
            float4 o;
            o.x = fmaxf(0.f, fmaf(d0 * rs, g4.x, lb4.x));
            o.y = fmaxf(0.f, fmaf(d1 * rs, g4.y, lb4.y));
            o.z = fmaxf(0.f, fmaf(d2 * rs, g4.z, lb4.z));
            o.w = fmaxf(0.f, fmaf(d3 * rs, g4.w, lb4.w));
            int row = rowbase + rg * 8 + j;
            if (row < N)
                *(float4*)(h + (size_t)row * HDIM + c0) = o;
            float cs = csArr[j], cd = cdArr[j];
            accS.x = fmaf(cs, o.x, accS.x); accS.y = fmaf(cs, o.y, accS.y);
            accS.z = fmaf(cs, o.z, accS.z); accS.w = fmaf(cs, o.w, accS.w);
            accD.x = fmaf(cd, o.x, accD.x); accD.y = fmaf(cd, o.y, accD.y);
            accD.z = fmaf(cd, o.z, accD.z); accD.w = fmaf(cd, o.w, accD.w);
        }
    }
    __syncthreads();
    float* red = xl;
    *(float4*)(red + rg * HDIM + c0) = accS;
    *(float4*)(red + 1024 + rg * HDIM + c0) = accD;
    __syncthreads();
    if (t < 128) {
        float s = 0.f, d = 0.f;
#pragma unroll
        for (int gi = 0; gi < 8; ++gi) {
            s += red[gi * HDIM + t];
            d += red[1024 + gi * HDIM + t];
        }
        float* row = partials + (size_t)blockIdx.x * 512;
        row[t] = s;        row[t + 128] = 0.f;
        row[t + 256] = d;  row[t + 384] = 0.f;
    }
}

// ---------------- LN helper ----------------
__device__ __forceinline__ float2 ln_relu2(float2 v, float2 g, float2 bb) {
    float s = v.x + v.y;
#pragma unroll
    for (int m = 32; m; m >>= 1) s += __shfl_xor(s, m);
    float mu = s * (1.0f / HDIM);
    float dx = v.x - mu, dy = v.y - mu;
    float q = dx * dx + dy * dy;
#pragma unroll
    for (int m = 32; m; m >>= 1) q += __shfl_xor(q, m);
    float rs = rsqrtf(q * (1.0f / HDIM) + LN_EPS);
    float2 o;
    o.x = fmaxf(0.f, fmaf(dx * rs, g.x, bb.x));
    o.y = fmaxf(0.f, fmaf(dy * rs, g.y, bb.y));
    return o;
}

// ---------------- K8: h = relu(LN(h + mm)); next-layer sums or pooling ----------------
template <int LAST>
__global__ __launch_bounds__(256) void k_update(
        float* __restrict__ h, const float* __restrict__ mean_msg,
        const float* __restrict__ ln_g, const float* __restrict__ ln_b,
        const float* __restrict__ c_src, const float* __restrict__ c_dst,
        const int* __restrict__ batch, float* __restrict__ partials,
        float* __restrict__ pooled, int N, int cpb) {
    int t = threadIdx.x;
    int lane = t & 63, w = t >> 6;
    int c0 = lane * 2;
    float2 mm = *(const float2*)(mean_msg + c0);
    float2 g  = *(const float2*)(ln_g + c0);
    float2 bb = *(const float2*)(ln_b + c0);
    int start = blockIdx.x * cpb;
    int end = min(N, start + cpb);
    int spw = (cpb + 3) >> 2;
    int ns = start + w * spw;
    int ne = min(end, ns + spw);
    float2 accS = {0.f, 0.f}, accD = {0.f, 0.f}, accP = {0.f, 0.f};
    int cur_g = -1;
    int n = ns;
    for (; n + 4 <= ne; n += 4) {
        float2 v0 = *(const float2*)(h + (size_t)(n    ) * HDIM + c0);
        float2 v1 = *(const float2*)(h + (size_t)(n + 1) * HDIM + c0);
        float2 v2 = *(const float2*)(h + (size_t)(n + 2) * HDIM + c0);
        float2 v3 = *(const float2*)(h + (size_t)(n + 3) * HDIM + c0);
        v0.x += mm.x; v0.y += mm.y;  v1.x += mm.x; v1.y += mm.y;
        v2.x += mm.x; v2.y += mm.y;  v3.x += mm.x; v3.y += mm.y;
        float2 o0 = ln_relu2(v0, g, bb);
        float2 o1 = ln_relu2(v1, g, bb);
        float2 o2 = ln_relu2(v2, g, bb);
        float2 o3 = ln_relu2(v3, g, bb);
        if (LAST) {
            int gi[4] = {batch[n], batch[n + 1], batch[n + 2], batch[n + 3]};
            float2 oo[4] = {o0, o1, o2, o3};
#pragma unroll
            for (int r = 0; r < 4; ++r) {
                if (gi[r] != cur_g) {
                    if (cur_g >= 0) {
                        atomicAdd(&pooled[cur_g * HDIM + c0],     accP.x);
                        atomicAdd(&pooled[cur_g * HDIM + c0 + 1], accP.y);
                    }
                    accP.x = 0.f; accP.y = 0.f;
                    cur_g = gi[r];
                }
                accP.x += oo[r].x; accP.y += oo[r].y;
            }
        } else {
            *(float2*)(h + (size_t)(n    ) * HDIM + c0) = o0;
            *(float2*)(h + (size_t)(n + 1) * HDIM + c0) = o1;
            *(float2*)(h + (size_t)(n + 2) * HDIM + c0) = o2;
            *(float2*)(h + (size_t)(n + 3) * HDIM + c0) = o3;
            float cs0 = c_src[n], cs1 = c_src[n+1], cs2 = c_src[n+2], cs3 = c_src[n+3];
            float cd0 = c_dst[n], cd1 = c_dst[n+1], cd2 = c_dst[n+2], cd3 = c_dst[n+3];
            accS.x = fmaf(cs0, o0.x, accS.x); accS.y = fmaf(cs0, o0.y, accS.y);
            accS.x = fmaf(cs1, o1.x, accS.x); accS.y = fmaf(cs1, o1.y, accS.y);
            accS.x = fmaf(cs2, o2.x, accS.x); accS.y = fmaf(cs2, o2.y, accS.y);
            accS.x = fmaf(cs3, o3.x, accS.x); accS.y = fmaf(cs3, o3.y, accS.y);
            accD.x = fmaf(cd0, o0.x, accD.x); accD.y = fmaf(cd0, o0.y, accD.y);
            accD.x = fmaf(cd1, o1.x, accD.x); accD.y = fmaf(cd1, o1.y, accD.y);
            accD.x = fmaf(cd2, o2.x, accD.x); accD.y = fmaf(cd2, o2.y, accD.y);
            accD.x = fmaf(cd3, o3.x, accD.x); accD.y = fmaf(cd3, o3.y, accD.y);
        }
    }
    for (; n < ne; ++n) {
        float2 v = *(const float2*)(h + (size_t)n * HDIM + c0);
        v.x += mm.x; v.y += mm.y;
        float2 o = ln_relu2(v, g, bb);
        if (LAST) {
            int gg = batch[n];
            if (gg != cur_g) {
                if (cur_g >= 0) {
                    atomicAdd(&pooled[cur_g * HDIM + c0],     accP.x);
                    atomicAdd(&pooled[cur_g * HDIM + c0 + 1], accP.y);
                }
                accP.x = 0.f; accP.y = 0.f;
                cur_g = gg;
            }
            accP.x += o.x; accP.y += o.y;
        } else {
            *(float2*)(h + (size_t)n * HDIM + c0) = o;
            float cs = c_src[n], cd = c_dst[n];
            accS.x = fmaf(cs, o.x, accS.x); accS.y = fmaf(cs, o.y, accS.y);
            accD.x = fmaf(cd, o.x, accD.x); accD.y = fmaf(cd, o.y, accD.y);
        }
    }
    if (LAST) {
        if (cur_g >= 0) {
            atomicAdd(&pooled[cur_g * HDIM + c0],     accP.x);
            atomicAdd(&pooled[cur_g * HDIM + c0 + 1], accP.y);
        }
    } else {
        __shared__ float sb[HDIM], db[HDIM];
        if (t < HDIM) { sb[t] = 0.f; db[t] = 0.f; }
        __syncthreads();
        atomicAdd(&sb[c0], accS.x); atomicAdd(&sb[c0 + 1], accS.y);
        atomicAdd(&db[c0], accD.x); atomicAdd(&db[c0 + 1], accD.y);
        __syncthreads();
        float* row = partials + (size_t)blockIdx.x * 512;
        if (t < 128) {
            row[t] = sb[t];        row[t + 128] = 0.f;
            row[t + 256] = db[t];  row[t + 384] = 0.f;
        }
    }
}

// ---------------- K9: out = (pooled / max(cnt,1)) @ w_out + b_out ----------------
__global__ __launch_bounds__(128) void k_out(const float* __restrict__ pooled,
        const int* __restrict__ batch, const float* __restrict__ w_out,
        const float* __restrict__ b_out, float* __restrict__ out, int N) {
    int gph = blockIdx.x;
    int t = threadIdx.x;
    __shared__ float p[HDIM];
    __shared__ int cntS;
    if (t == 0) {
        int lo = 0, hi = N;
        while (lo < hi) { int mid = (lo + hi) >> 1; if (batch[mid] < gph) lo = mid + 1; else hi = mid; }
        int lo2 = lo, hi2 = N;
        while (lo2 < hi2) { int mid = (lo2 + hi2) >> 1; if (batch[mid] <= gph) lo2 = mid + 1; else hi2 = mid; }
        cntS = lo2 - lo;
    }
    __syncthreads();
    float inv = 1.0f / fmaxf((float)cntS, 1.0f);
    p[t] = pooled[gph * HDIM + t] * inv;
    __syncthreads();
    float acc = b_out[t];
#pragma unroll 8
    for (int k = 0; k < HDIM; ++k) acc = fmaf(p[k], w_out[k * HDIM + t], acc);
    out[gph * HDIM + t] = acc;
}

extern "C" void kernel_launch(void* const* d_in, const int* in_sizes, int n_in,
                              void* d_out, int out_size, void* d_ws, size_t ws_size,
                              hipStream_t stream) {
    const float* x      = (const float*)d_in[0];
    const int*   ei     = (const int*)d_in[1];
    const float* ea     = (const float*)d_in[2];
    const int*   batch  = (const int*)d_in[3];
    const float* w_node = (const float*)d_in[4];
    const float* b_node = (const float*)d_in[5];
    const float* w_edge = (const float*)d_in[6];
    const float* b_edge = (const float*)d_in[7];
    const float* mp_w   = (const float*)d_in[8];
    const float* mp_b   = (const float*)d_in[9];
    const float* ln_g   = (const float*)d_in[10];
    const float* ln_b   = (const float*)d_in[11];
    const float* w_out  = (const float*)d_in[12];
    const float* b_out  = (const float*)d_in[13];
    float* out = (float*)d_out;
    int N = in_sizes[3];
    int E = in_sizes[2] / EDIM;
    float Ef = (float)E;
    int ntiles = (N + T0ROWS - 1) / T0ROWS;

    float* ws = (float*)d_ws;
    size_t off = 0;
    float* h        = ws + off; off += (size_t)N * HDIM;       // hist partials overlay here
    float* hist_part = h;   // 26.2MB <= 51.2MB
    float* partials = ws + off; off += (size_t)1024 * 512;
    float* mean_msg = ws + off; off += 128;
    float* c_src    = ws + off; off += CBINS;
    float* c_dst    = ws + off; off += CBINS;
    float* xpart    = ws + off; off += (size_t)NBX * 136;      // fully written by k_xsum
    float* xs       = ws + off; off += 136;                    // fully written by k_xred
    // ---- accumulator region (contiguous, zeroed every call) ----
    float* acc0     = ws + off;
    float* sum_attr = ws + off; off += 8;
    float* sbuf1    = ws + off; off += 512;
    float* sbuf2    = ws + off; off += 512;
    float* pooled   = ws + off; off += NGRAPHS * HDIM;
    size_t zero_count = (size_t)(ws + off - acc0);
    hipMemsetAsync(acc0, 0, zero_count * sizeof(float), stream);

    k_hist_part<<<2 * HR * HB, 256, 0, stream>>>(ei, hist_part, E);
    k_hist_red<<<(CBINS + 255) / 256, 256, 0, stream>>>(hist_part, c_src, c_dst);
    k_edgesum<<<128, 256, 0, stream>>>(ea, sum_attr, E);
    k_xsum<<<NBX, 256, 0, stream>>>(x, c_src, c_dst, xpart, N);
    k_xred<<<2 * XDIM, 64, 0, stream>>>(xpart, xs, NBX);

    const int NB0 = 768;
    const int NB = 1024;
    int cpb = (N + NB - 1) / NB;

    // layer 0
    k_mm<1><<<8, 256, 0, stream>>>(xs, sum_attr, w_edge, b_edge,
                                   mp_w, mp_b, mean_msg, Ef, w_node, b_node);
    k_upd0<<<NB0, 256, 0, stream>>>(x, w_node, b_node, mean_msg, ln_g, ln_b,
                                    c_src, c_dst, h, partials, N, ntiles);
    // layer 1
    k_red<<<(NB0 + 31) / 32, 256, 0, stream>>>(partials, sbuf1, NB0);
    k_mm<0><<<8, 256, 0, stream>>>(sbuf1, sum_attr, w_edge, b_edge,
                                   mp_w + (size_t)1 * 384 * HDIM,
                                   mp_b + (size_t)1 * HDIM, mean_msg, Ef,
                                   w_node, b_node);
    k_update<0><<<NB, 256, 0, stream>>>(h, mean_msg, ln_g, ln_b, c_src, c_dst,
                                        batch, partials, pooled, N, cpb);
    // layer 2
    k_red<<<NB / 32, 256, 0, stream>>>(partials, sbuf2, NB);
    k_mm<0><<<8, 256, 0, stream>>>(sbuf2, sum_attr, w_edge, b_edge,
                                   mp_w + (size_t)2 * 384 * HDIM,
                                   mp_b + (size_t)2 * HDIM, mean_msg, Ef,
                                   w_node, b_node);
    k_update<1><<<NB, 256, 0, stream>>>(h, mean_msg, ln_g, ln_b, c_src, c_dst,
                                        batch, partials, pooled, N, cpb);

    k_out<<<NGRAPHS, HDIM, 0, stream>>>(pooled, batch, w_out, b_out, out, N);
}